// Round 4
// baseline (301.990 us; speedup 1.0000x reference)
//
#include <hip/hip_runtime.h>
#include <hip/hip_bf16.h>

// Problem constants
#define BB 4
#define NN 1024
#define FF 512
#define HH 8
#define KK 64
#define PSZ ((size_t)BB * HH * NN * KK)        // 2,097,152 elements

// ws layout (u16 units)
#define XAOFF 0u
#define XBOFF 2097152u
#define WTOFF 4194304u                          // Wt[3][512][512] bf16
#define WOOFF (WTOFF + 786432u)                 // Wout bf16 [512][512]
#define PBOFF (WOOFF + 262144u)                 // 6 projection buffers
#define MSOFF (PBOFF + 6u * 2097152u)           // 4 msgs buffers (bf16)
#define ADOFF (MSOFF + 4u * 2097152u)           // adj bf16 (prescaled by log2e) [3][4][1024][1024]
#define ADSZ  4194304u                          // per adj matrix (u16)
// AinT (bf16, prescaled, transposed A_inter) overwrites the dead Xa/Xb region

#define LOG2E 1.4426950408889634f
#define SHIFT2 34.624683f                       // 24 * log2e

typedef unsigned short u16;
typedef __attribute__((ext_vector_type(8))) short bf16x8;
typedef __attribute__((ext_vector_type(4))) short bf16x4;
typedef __attribute__((ext_vector_type(4))) float f32x4;
typedef __attribute__((ext_vector_type(8))) unsigned short ushort8;
typedef __attribute__((ext_vector_type(4))) unsigned short ushort4v;

#if defined(__has_builtin)
#if __has_builtin(__builtin_amdgcn_mfma_f32_16x16x16bf16_1k)
#define HAVE_MFMA16 1
#endif
#if __has_builtin(__builtin_amdgcn_global_load_lds)
#define HAVE_GLL 1
#endif
#endif
#ifndef HAVE_MFMA16
#define HAVE_MFMA16 0
#endif
#ifndef HAVE_GLL
#define HAVE_GLL 0
#endif

#if HAVE_GLL
#define GSTR 64
#else
#define GSTR 72
#endif

__device__ __forceinline__ u16 f2b(float x) {
    union { float f; unsigned u; } v; v.f = x;
    unsigned r = v.u + 0x7FFF + ((v.u >> 16) & 1);   // RNE
    return (u16)(r >> 16);
}
__device__ __forceinline__ float b2f(u16 x) {
    union { unsigned u; float f; } v; v.u = ((unsigned)x) << 16;
    return v.f;
}

// ---------------------------------------------------------------------------
// Kernel 0: merged prep (streaming converts) + wt (W transpose).
// ---------------------------------------------------------------------------
__global__ __launch_bounds__(256) void prep_kernel(
    const float* __restrict__ Xa, const float* __restrict__ Xb,
    const float* __restrict__ Wout,
    const float* __restrict__ Aia, const float* __restrict__ Aib,
    const float* __restrict__ Ain,
    const float* __restrict__ W1, const float* __restrict__ W2,
    const float* __restrict__ W3,
    u16* __restrict__ ws)
{
    __shared__ float T[64][65];
    const int bid = blockIdx.x;
    const int t = threadIdx.x;

    if (bid < 192) {
        const int j  = bid / 64;
        const int rem = bid & 63;
        const int h  = rem >> 3;
        const int f0 = (rem & 7) * 64;
        const float* Wj = j == 0 ? W1 : (j == 1 ? W2 : W3);
        const int tr = t >> 2, tc = (t & 3) * 16;
        const float* src = Wj + (size_t)h * FF * KK + (size_t)(f0 + tr) * KK + tc;
        #pragma unroll
        for (int jj = 0; jj < 4; ++jj) {
            float4 v = *(const float4*)(src + 4 * jj);
            T[tr][tc + 4 * jj + 0] = v.x;
            T[tr][tc + 4 * jj + 1] = v.y;
            T[tr][tc + 4 * jj + 2] = v.z;
            T[tr][tc + 4 * jj + 3] = v.w;
        }
        __syncthreads();
        ushort8 w0, w1;
        #pragma unroll
        for (int jj = 0; jj < 8; ++jj) {
            w0[jj] = f2b(T[tc + jj][tr]);
            w1[jj] = f2b(T[tc + 8 + jj][tr]);
        }
        u16* d = ws + WTOFF + (unsigned)j * 262144u + (unsigned)(h * 64 + tr) * 512u + f0 + tc;
        *(ushort8*)&d[0] = w0;
        *(ushort8*)&d[8] = w1;
        return;
    }

    const int NFLAT4 = (2097152 + 2097152 + 262144) / 4;   // 1,114,112
    const int NADJ4  = 3 * 1048576;                        // 3,145,728
    const int total  = NFLAT4 + NADJ4;
    const int nb = gridDim.x - 192;
    for (int idx = (bid - 192) * 256 + t; idx < total; idx += nb * 256) {
        if (idx < NFLAT4) {
            int e = idx * 4;
            const float* src; u16* dst;
            if (e < 2097152)      { src = Xa + e;             dst = ws + XAOFF + e; }
            else if (e < 4194304) { src = Xb + (e - 2097152); dst = ws + XBOFF + (e - 2097152); }
            else                  { src = Wout + (e - 4194304); dst = ws + WOOFF + (e - 4194304); }
            float4 v = *(const float4*)src;
            ushort4v w;
            w[0] = f2b(v.x); w[1] = f2b(v.y); w[2] = f2b(v.z); w[3] = f2b(v.w);
            *(ushort4v*)dst = w;
        } else {
            int r = idx - NFLAT4;
            int z = r >> 20;
            int rem = r & 1048575;
            const float* src = (z == 0 ? Aia : (z == 1 ? Aib : Ain)) + (size_t)rem * 4;
            float4 v = *(const float4*)src;
            ushort4v w;
            w[0] = f2b(v.x * LOG2E); w[1] = f2b(v.y * LOG2E);
            w[2] = f2b(v.z * LOG2E); w[3] = f2b(v.w * LOG2E);
            *(ushort4v*)(ws + ADOFF + (size_t)z * ADSZ + (size_t)rem * 4) = w;
        }
    }
}

// ---------------------------------------------------------------------------
// Kernel 0b: AinT[b][c][r] = bf16(Ain[b][r][c] * log2e); into dead Xa/Xb region.
// ---------------------------------------------------------------------------
__global__ __launch_bounds__(256) void tr_kernel(const float* __restrict__ A, u16* __restrict__ dst)
{
    const int b = blockIdx.z;
    const int r0 = blockIdx.y * 64, c0 = blockIdx.x * 64;
    __shared__ float T[64][65];
    const int t = threadIdx.x;
    const int tr = t >> 2, tc = (t & 3) * 16;
    const float* src = A + ((size_t)b * NN + r0 + tr) * NN + c0 + tc;
    #pragma unroll
    for (int j = 0; j < 4; ++j) {
        float4 v = *(const float4*)(src + 4 * j);
        T[tr][tc + 4 * j + 0] = v.x;
        T[tr][tc + 4 * j + 1] = v.y;
        T[tr][tc + 4 * j + 2] = v.z;
        T[tr][tc + 4 * j + 3] = v.w;
    }
    __syncthreads();
    ushort8 w0, w1;
    #pragma unroll
    for (int j = 0; j < 8; ++j) {
        w0[j] = f2b(T[tc + j][tr] * LOG2E);
        w1[j] = f2b(T[tc + 8 + j][tr] * LOG2E);
    }
    u16* d = dst + ((size_t)b * NN + c0 + tr) * NN + r0 + tc;
    *(ushort8*)&d[0] = w0;
    *(ushort8*)&d[8] = w1;
}

// ---------------------------------------------------------------------------
// Kernel 1: MFMA projections. z = src*3 + pj. 128x128 tile, 4 waves (2x2).
// ---------------------------------------------------------------------------
__global__ __launch_bounds__(256) void proj_kernel(
    const float* __restrict__ b1v, const float* __restrict__ b2v,
    const float* __restrict__ b3v,
    u16* __restrict__ ws)
{
    const int z  = blockIdx.z;
    const int src = z / 3, pj = z % 3;
    const u16* X  = ws + (src ? XBOFF : XAOFF);
    const u16* Wt = ws + WTOFF + (unsigned)pj * 262144u;
    const float* bias = pj == 0 ? b1v : (pj == 1 ? b2v : b3v);
    u16* P = ws + PBOFF + (size_t)z * PSZ;

    const int rb = blockIdx.y * 128;
    const int cb = blockIdx.x * 128;
    const int t  = threadIdx.x;
    const int lane = t & 63, wave = t >> 6;
    const int lg = lane >> 4, li = lane & 15;
    const int wr = wave >> 1, wc = wave & 1;

    __shared__ u16 As[128 * GSTR];
    __shared__ u16 Bs[128 * GSTR];

    f32x4 acc[4][4];
    #pragma unroll
    for (int m = 0; m < 4; ++m)
        #pragma unroll
        for (int n = 0; n < 4; ++n) acc[m][n] = (f32x4){0.f, 0.f, 0.f, 0.f};

#if !HAVE_GLL
    const int srow = t >> 1, sf0 = (t & 1) * 32;
#endif

    for (int fb = 0; fb < FF; fb += 64) {
        __syncthreads();
#if HAVE_GLL
        {
            const int gr = wave * 32 + (lane >> 3);
            const int gc = (lane & 7) * 8;
            #pragma unroll
            for (int i = 0; i < 4; ++i) {
                __builtin_amdgcn_global_load_lds(
                    (const unsigned int*)&X[(size_t)(rb + gr + 8 * i) * FF + fb + gc],
                    (unsigned int*)&As[(wave * 32 + 8 * i) * GSTR], 16, 0, 0);
                __builtin_amdgcn_global_load_lds(
                    (const unsigned int*)&Wt[(size_t)(cb + gr + 8 * i) * FF + fb + gc],
                    (unsigned int*)&Bs[(wave * 32 + 8 * i) * GSTR], 16, 0, 0);
            }
        }
#else
        #pragma unroll
        for (int s = 0; s < 4; ++s) {
            *(ushort8*)&As[srow * GSTR + sf0 + 8 * s] =
                *(const ushort8*)&X[(size_t)(rb + srow) * FF + fb + sf0 + 8 * s];
            *(ushort8*)&Bs[srow * GSTR + sf0 + 8 * s] =
                *(const ushort8*)&Wt[(size_t)(cb + srow) * FF + fb + sf0 + 8 * s];
        }
#endif
        __syncthreads();

        bf16x8 af[4][2], bf[4][2];
        #pragma unroll
        for (int m = 0; m < 4; ++m) {
            af[m][0] = *(const bf16x8*)&As[(wr * 64 + m * 16 + li) * GSTR + 8 * lg];
            af[m][1] = *(const bf16x8*)&As[(wr * 64 + m * 16 + li) * GSTR + 8 * lg + 32];
        }
        #pragma unroll
        for (int n = 0; n < 4; ++n) {
            bf[n][0] = *(const bf16x8*)&Bs[(wc * 64 + n * 16 + li) * GSTR + 8 * lg];
            bf[n][1] = *(const bf16x8*)&Bs[(wc * 64 + n * 16 + li) * GSTR + 8 * lg + 32];
        }
        #pragma unroll
        for (int m = 0; m < 4; ++m)
            #pragma unroll
            for (int n = 0; n < 4; ++n) {
                acc[m][n] = __builtin_amdgcn_mfma_f32_16x16x32_bf16(af[m][0], bf[n][0], acc[m][n], 0, 0, 0);
                acc[m][n] = __builtin_amdgcn_mfma_f32_16x16x32_bf16(af[m][1], bf[n][1], acc[m][n], 0, 0, 0);
            }
    }

    if (pj != 2) {
        #pragma unroll
        for (int m = 0; m < 4; ++m)
            #pragma unroll
            for (int n = 0; n < 4; ++n)
                #pragma unroll
                for (int r = 0; r < 4; ++r) {
                    int row = rb + wr * 64 + m * 16 + 4 * lg + r;
                    int col = cb + wc * 64 + n * 16 + li;
                    int b_ = row >> 10, n_ = row & 1023;
                    int h = col >> 6, k = col & 63;
                    P[((size_t)(b_ * HH + h) * NN + n_) * KK + k] = f2b(acc[m][n][r] + bias[col]);
                }
    } else {
        #pragma unroll
        for (int m = 0; m < 4; ++m)
            #pragma unroll
            for (int n = 0; n < 4; ++n) {
                int col = cb + wc * 64 + n * 16 + li;
                int h = col >> 6, k = col & 63;
                int row0 = rb + wr * 64 + m * 16 + 4 * lg;
                int b_ = row0 >> 10, n0 = row0 & 1023;
                float bsv = bias[col];
                ushort4v w;
                #pragma unroll
                for (int r = 0; r < 4; ++r) w[r] = f2b(acc[m][n][r] + bsv);
                *(ushort4v*)&P[((size_t)(b_ * HH + h) * KK + k) * NN + n0] = w;
            }
    }
}

// ---------------------------------------------------------------------------
// Kernel 2: MFMA flash attention — round-2 preamble (known-good), loop with
// ZERO LDS and ZERO barriers: K, V (pre-transposed), and adj fragments are
// read directly global->register. Rationale (r3 post-mortem): the loop was
// LDS-pipe-bound (~86k cy/CU of LDS issue + 36k conflict cy vs 165k total);
// K/V panels are 128KB and L2-resident (shared by the 8 same-XCD q-blocks),
// adj is a single-use stream — staging them through LDS was pure overhead
// (m169 pattern). All reads are cache-line-complete per wave. No barriers
// => compiler pipelines across iterations freely.
// ---------------------------------------------------------------------------
__global__ __launch_bounds__(256, 4) void attn_kernel(
    const u16* __restrict__ Pbase,
    const float* __restrict__ Wia, const float* __restrict__ Wib, const float* __restrict__ Win,
    const u16* __restrict__ AD, const u16* __restrict__ AinT,
    u16* __restrict__ msgs)
{
    // hw flat id -> logical (q, bh, agg); 1024 = 8 XCD chunks x 128
    const int flat = blockIdx.x;
    const int lf   = (flat & 7) * 128 + (flat >> 3);
    const int qb   = (lf & 7) * 128;
    const int bh   = (lf >> 3) & 31;
    const int agg  = lf >> 8;
    const int b = bh >> 3, h = bh & 7;
    const int t = threadIdx.x;
    const int lane = t & 63, wave = t >> 6;
    const int lg = lane >> 4, li = lane & 15;

    const u16 *Qp, *Kp, *Vp, *adj; const float* ew;
    switch (agg) {
      case 0: Qp = Pbase;         ew = Wia; Kp = Pbase + 1*PSZ; Vp = Pbase + 2*PSZ; adj = AD;          break;
      case 1: Qp = Pbase + 3*PSZ; ew = Wib; Kp = Pbase + 4*PSZ; Vp = Pbase + 5*PSZ; adj = AD + 1*ADSZ; break;
      case 2: Qp = Pbase;         ew = Win; Kp = Pbase + 4*PSZ; Vp = Pbase + 2*PSZ; adj = AD + 2*ADSZ; break;
      default:Qp = Pbase + 3*PSZ; ew = Win; Kp = Pbase + 1*PSZ; Vp = Pbase + 5*PSZ; adj = AinT;        break;
    }
    const size_t bhoff = (size_t)(b * HH + h) * NN * KK;
    const u16* Qbh  = Qp + bhoff;       // [n][k] bf16
    const u16* Kbh  = Kp + bhoff;       // [n][k] bf16
    const u16* Vbh  = Vp + bhoff;       // [k][n] bf16 (pre-transposed)
    const u16* adjb = adj + (size_t)b * NN * NN;   // mask[q][m] bf16 (prescaled)

    __shared__ u16 Qa[128 * 72];        // preamble Q-out staging
    __shared__ u16 Kt[64 * 72];         // preamble F1-half staging
    __shared__ u16 Vt[64 * 72];         // preamble ewT

    const int sr  = t >> 2;             // 0..63
    const int sc  = (t & 3) * 16;

    // ---------------- preamble: Q = F1 @ ew for 128 rows ----------------
    #pragma unroll
    for (int j = 0; j < 16; ++j)        // Vt[l][k'] = ew[k'][l]
        Vt[(sc + j) * 72 + sr] = f2b(ew[sr * 64 + sc + j]);

    #pragma unroll
    for (int p = 0; p < 2; ++p) {
        __syncthreads();
        {
            const ushort8* src = (const ushort8*)&Qbh[(size_t)(qb + p * 64 + sr) * KK + sc];
            *(ushort8*)&Kt[sr * 72 + sc]     = src[0];
            *(ushort8*)&Kt[sr * 72 + sc + 8] = src[1];
        }
        __syncthreads();
        bf16x8 a0 = *(const bf16x8*)&Kt[(wave * 16 + li) * 72 + 8 * lg];
        bf16x8 a1 = *(const bf16x8*)&Kt[(wave * 16 + li) * 72 + 8 * lg + 32];
        #pragma unroll
        for (int t_ = 0; t_ < 4; ++t_) {
            bf16x8 b0 = *(const bf16x8*)&Vt[(li + 16 * t_) * 72 + 8 * lg];
            bf16x8 b1 = *(const bf16x8*)&Vt[(li + 16 * t_) * 72 + 8 * lg + 32];
            f32x4 q = {0.f, 0.f, 0.f, 0.f};
            q = __builtin_amdgcn_mfma_f32_16x16x32_bf16(a0, b0, q, 0, 0, 0);
            q = __builtin_amdgcn_mfma_f32_16x16x32_bf16(a1, b1, q, 0, 0, 0);
            #pragma unroll
            for (int r = 0; r < 4; ++r)
                Qa[(p * 64 + wave * 16 + 4 * lg + r) * 72 + li + 16 * t_] = f2b(q[r]);
        }
    }
    __syncthreads();
    bf16x8 qB[2][2];
    #pragma unroll
    for (int u = 0; u < 2; ++u)
        #pragma unroll
        for (int c = 0; c < 2; ++c)
            qB[u][c] = *(const bf16x8*)&Qa[(wave * 32 + u * 16 + li) * 72 + 32 * c + 8 * lg];

    f32x4 oacc[2][4];
    #pragma unroll
    for (int u = 0; u < 2; ++u)
        #pragma unroll
        for (int f_ = 0; f_ < 4; ++f_) oacc[u][f_] = (f32x4){0.f, 0.f, 0.f, 0.f};
    float lsum[2] = {0.f, 0.f};

#if HAVE_MFMA16
    // -------------------- barrier-free, LDS-free main loop --------------------
    const int q0 = qb + wave * 32 + li;             // adj row base (u=0)
    #pragma unroll 1
    for (int mt = 0; mt < 16; ++mt) {
        const int mb = mt * 64;

        // adj fragments: global -> reg (b64, line-complete per wave)
        ushort4v adv[2][4];
        #pragma unroll
        for (int u = 0; u < 2; ++u)
            #pragma unroll
            for (int t_ = 0; t_ < 4; ++t_)
                adv[u][t_] = *(const ushort4v*)&adjb[(size_t)(q0 + u * 16) * NN + mb + 16 * t_ + 4 * lg];

        // ---- S^T + masked exp2 + cvt_pk pack; K frags direct from global ----
        bf16x4 pa[2][4];
        #pragma unroll
        for (int t_ = 0; t_ < 4; ++t_) {
            const u16* krow = &Kbh[(size_t)(mb + li + 16 * t_) * KK + 8 * lg];
            bf16x8 kb0 = *(const bf16x8*)&krow[0];
            bf16x8 kb1 = *(const bf16x8*)&krow[32];
            #pragma unroll
            for (int u = 0; u < 2; ++u) {
                f32x4 s = {0.f, 0.f, 0.f, 0.f};
                __builtin_amdgcn_s_setprio(1);
                s = __builtin_amdgcn_mfma_f32_16x16x32_bf16(kb0, qB[u][0], s, 0, 0, 0);
                s = __builtin_amdgcn_mfma_f32_16x16x32_bf16(kb1, qB[u][1], s, 0, 0, 0);
                __builtin_amdgcn_s_setprio(0);
                float p0 = __builtin_amdgcn_exp2f(fmaf(s[0], b2f(adv[u][t_][0]), -SHIFT2));
                float p1 = __builtin_amdgcn_exp2f(fmaf(s[1], b2f(adv[u][t_][1]), -SHIFT2));
                float p2 = __builtin_amdgcn_exp2f(fmaf(s[2], b2f(adv[u][t_][2]), -SHIFT2));
                float p3 = __builtin_amdgcn_exp2f(fmaf(s[3], b2f(adv[u][t_][3]), -SHIFT2));
                lsum[u] += (p0 + p1) + (p2 + p3);
                unsigned w0, w1;
                asm("v_cvt_pk_bf16_f32 %0, %1, %2" : "=v"(w0) : "v"(p0), "v"(p1));
                asm("v_cvt_pk_bf16_f32 %0, %1, %2" : "=v"(w1) : "v"(p2), "v"(p3));
                union { uint2 u2; bf16x4 v; } pk;
                pk.u2.x = w0; pk.u2.y = w1;
                pa[u][t_] = pk.v;
            }
        }

        // ---- O += P @ V; V frags (b64) direct from global ----
        __builtin_amdgcn_s_setprio(1);
        #pragma unroll
        for (int f_ = 0; f_ < 4; ++f_) {
            const u16* vrow = &Vbh[(size_t)(li + 16 * f_) * NN + mb + 4 * lg];
            #pragma unroll
            for (int t_ = 0; t_ < 4; ++t_) {
                bf16x4 vb = *(const bf16x4*)&vrow[16 * t_];
                oacc[0][f_] = __builtin_amdgcn_mfma_f32_16x16x16bf16_1k(pa[0][t_], vb, oacc[0][f_], 0, 0, 0);
                oacc[1][f_] = __builtin_amdgcn_mfma_f32_16x16x16bf16_1k(pa[1][t_], vb, oacc[1][f_], 0, 0, 0);
            }
        }
        __builtin_amdgcn_s_setprio(0);
    }
#else
    // -------- fallback: round-2 LDS-staged loop (non-gfx950 only) --------
    __syncthreads();
    const int sr2 = t >> 1;
    const int sc2 = (t & 1) * 32;
    for (int mt = 0; mt < 16; ++mt) {
        const int mb = mt * 64;
        {
            const ushort8* ks = (const ushort8*)&Kbh[(size_t)(mb + sr) * KK + sc];
            *(ushort8*)&Kt[sr * 72 + sc]     = ks[0];
            *(ushort8*)&Kt[sr * 72 + sc + 8] = ks[1];
            const ushort8* vs = (const ushort8*)&Vbh[(size_t)sr * NN + mb + sc];
            *(ushort8*)&Vt[sr * 72 + sc]     = vs[0];
            *(ushort8*)&Vt[sr * 72 + sc + 8] = vs[1];
            const u16* ap = &adjb[(size_t)(qb + sr2) * NN + mb + sc2];
            #pragma unroll
            for (int s = 0; s < 4; ++s)
                *(ushort8*)&Qa[sr2 * 72 + sc2 + 8 * s] = *(const ushort8*)&ap[8 * s];
        }
        __syncthreads();

        ushort4v adv[2][4];
        #pragma unroll
        for (int u = 0; u < 2; ++u)
            #pragma unroll
            for (int t_ = 0; t_ < 4; ++t_)
                adv[u][t_] = *(const ushort4v*)&Qa[(wave * 32 + u * 16 + li) * 72 + 16 * t_ + 4 * lg];

        #pragma unroll
        for (int t_ = 0; t_ < 4; ++t_) {
            bf16x8 kb0 = *(const bf16x8*)&Kt[(li + 16 * t_) * 72 + 8 * lg];
            bf16x8 kb1 = *(const bf16x8*)&Kt[(li + 16 * t_) * 72 + 8 * lg + 32];
            #pragma unroll
            for (int u = 0; u < 2; ++u) {
                f32x4 s = {0.f, 0.f, 0.f, 0.f};
                s = __builtin_amdgcn_mfma_f32_16x16x32_bf16(kb0, qB[u][0], s, 0, 0, 0);
                s = __builtin_amdgcn_mfma_f32_16x16x32_bf16(kb1, qB[u][1], s, 0, 0, 0);
                float p0 = __builtin_amdgcn_exp2f(fmaf(s[0], b2f(adv[u][t_][0]), -SHIFT2));
                float p1 = __builtin_amdgcn_exp2f(fmaf(s[1], b2f(adv[u][t_][1]), -SHIFT2));
                float p2 = __builtin_amdgcn_exp2f(fmaf(s[2], b2f(adv[u][t_][2]), -SHIFT2));
                float p3 = __builtin_amdgcn_exp2f(fmaf(s[3], b2f(adv[u][t_][3]), -SHIFT2));
                lsum[u] += (p0 + p1) + (p2 + p3);
                unsigned w0, w1;
                asm("v_cvt_pk_bf16_f32 %0, %1, %2" : "=v"(w0) : "v"(p0), "v"(p1));
                asm("v_cvt_pk_bf16_f32 %0, %1, %2" : "=v"(w1) : "v"(p2), "v"(p3));
                uint2 pd; pd.x = w0; pd.y = w1;
                *(uint2*)&Qa[(wave * 32 + u * 16 + li) * 72 + 16 * t_ + 4 * lg] = pd;
            }
        }
        {
            bf16x8 pA[2][2];
            #pragma unroll
            for (int u = 0; u < 2; ++u) {
                pA[u][0] = *(const bf16x8*)&Qa[(wave * 32 + u * 16 + li) * 72 + 8 * lg];
                pA[u][1] = *(const bf16x8*)&Qa[(wave * 32 + u * 16 + li) * 72 + 8 * lg + 32];
            }
            #pragma unroll
            for (int f_ = 0; f_ < 4; ++f_) {
                bf16x8 vb0 = *(const bf16x8*)&Vt[(li + 16 * f_) * 72 + 8 * lg];
                bf16x8 vb1 = *(const bf16x8*)&Vt[(li + 16 * f_) * 72 + 8 * lg + 32];
                #pragma unroll
                for (int u = 0; u < 2; ++u) {
                    oacc[u][f_] = __builtin_amdgcn_mfma_f32_16x16x32_bf16(pA[u][0], vb0, oacc[u][f_], 0, 0, 0);
                    oacc[u][f_] = __builtin_amdgcn_mfma_f32_16x16x32_bf16(pA[u][1], vb1, oacc[u][f_], 0, 0, 0);
                }
            }
        }
        __syncthreads();
    }
#endif

    // ---- epilogue: reduce l over 16-lane groups, normalize, write msgs ----
    #pragma unroll
    for (int u = 0; u < 2; ++u) {
        lsum[u] += __shfl_xor(lsum[u], 16);
        lsum[u] += __shfl_xor(lsum[u], 32);
    }
    #pragma unroll
    for (int u = 0; u < 2; ++u)
        #pragma unroll
        for (int r = 0; r < 4; ++r) {
            float inv = 1.f / __shfl(lsum[u], 4 * lg + r);
            int row = qb + wave * 32 + u * 16 + 4 * lg + r;
            u16* dst = msgs + (size_t)agg * PSZ + ((size_t)b * NN + row) * (HH * KK) + h * KK;
            #pragma unroll
            for (int f_ = 0; f_ < 4; ++f_)
                dst[li + 16 * f_] = f2b(oacc[u][f_][r] * inv);
        }
}

// ---------------------------------------------------------------------------
// Kernel 3: MFMA output projection, 64x128 tile (512 blocks = 2/CU).
// ---------------------------------------------------------------------------
__global__ __launch_bounds__(256) void out_kernel(
    const u16* __restrict__ ws,
    const float* __restrict__ bo, const float* __restrict__ bo2,
    float* __restrict__ out)
{
    const int z  = blockIdx.z;
    const u16* M1 = ws + MSOFF + (size_t)z * PSZ;
    const u16* M2 = ws + MSOFF + (size_t)(2 + z) * PSZ;
    const u16* Wb = ws + WOOFF;
    const int rb = blockIdx.y * 64;
    const int cb = blockIdx.x * 128;
    const int t  = threadIdx.x;
    const int lane = t & 63, wave = t >> 6;
    const int lg = lane >> 4, li = lane & 15;
    const int wr = wave >> 1, wc = wave & 1;

    __shared__ u16 A1s[64 * GSTR];
    __shared__ u16 A2s[64 * GSTR];
    __shared__ u16 Bs[128 * GSTR];

    f32x4 acc1[2][4], acc2[2][4];
    #pragma unroll
    for (int m = 0; m < 2; ++m)
        #pragma unroll
        for (int n = 0; n < 4; ++n) {
            acc1[m][n] = (f32x4){0.f, 0.f, 0.f, 0.f};
            acc2[m][n] = (f32x4){0.f, 0.f, 0.f, 0.f};
        }

    for (int fb = 0; fb < FF; fb += 64) {
        __syncthreads();
#if HAVE_GLL
        {
            const int lr = lane >> 3;
            const int gc = (lane & 7) * 8;
            #pragma unroll
            for (int i = 0; i < 2; ++i) {
                __builtin_amdgcn_global_load_lds(
                    (const unsigned int*)&M1[(size_t)(rb + wave * 16 + 8 * i + lr) * FF + fb + gc],
                    (unsigned int*)&A1s[(wave * 16 + 8 * i) * GSTR], 16, 0, 0);
                __builtin_amdgcn_global_load_lds(
                    (const unsigned int*)&M2[(size_t)(rb + wave * 16 + 8 * i + lr) * FF + fb + gc],
                    (unsigned int*)&A2s[(wave * 16 + 8 * i) * GSTR], 16, 0, 0);
            }
            #pragma unroll
            for (int i = 0; i < 4; ++i) {
                __builtin_amdgcn_global_load_lds(
                    (const unsigned int*)&Wb[(size_t)(cb + wave * 32 + 8 * i + lr) * FF + fb + gc],
                    (unsigned int*)&Bs[(wave * 32 + 8 * i) * GSTR], 16, 0, 0);
            }
        }
#else
        {
            int ar = t >> 2, ac = (t & 3) * 16;
            *(ushort8*)&A1s[ar * GSTR + ac]     = *(const ushort8*)&M1[(size_t)(rb + ar) * FF + fb + ac];
            *(ushort8*)&A1s[ar * GSTR + ac + 8] = *(const ushort8*)&M1[(size_t)(rb + ar) * FF + fb + ac + 8];
            *(ushort8*)&A2s[ar * GSTR + ac]     = *(const ushort8*)&M2[(size_t)(rb + ar) * FF + fb + ac];
            *(ushort8*)&A2s[ar * GSTR + ac + 8] = *(const ushort8*)&M2[(size_t)(rb + ar) * FF + fb + ac + 8];
            int br = t >> 1, bc = (t & 1) * 32;
            #pragma unroll
            for (int s = 0; s < 4; ++s)
                *(ushort8*)&Bs[br * GSTR + bc + 8 * s] =
                    *(const ushort8*)&Wb[(size_t)(cb + br) * FF + fb + bc + 8 * s];
        }
#endif
        __syncthreads();

        #pragma unroll
        for (int m = 0; m < 2; ++m) {
            bf16x8 a10 = *(const bf16x8*)&A1s[(wr * 32 + m * 16 + li) * GSTR + 8 * lg];
            bf16x8 a11 = *(const bf16x8*)&A1s[(wr * 32 + m * 16 + li) * GSTR + 8 * lg + 32];
            bf16x8 a20 = *(const bf16x8*)&A2s[(wr * 32 + m * 16 + li) * GSTR + 8 * lg];
            bf16x8 a21 = *(const bf16x8*)&A2s[(wr * 32 + m * 16 + li) * GSTR + 8 * lg + 32];
            #pragma unroll
            for (int n = 0; n < 4; ++n) {
                bf16x8 b0 = *(const bf16x8*)&Bs[(wc * 64 + n * 16 + li) * GSTR + 8 * lg];
                bf16x8 b1 = *(const bf16x8*)&Bs[(wc * 64 + n * 16 + li) * GSTR + 8 * lg + 32];
                acc1[m][n] = __builtin_amdgcn_mfma_f32_16x16x32_bf16(a10, b0, acc1[m][n], 0, 0, 0);
                acc1[m][n] = __builtin_amdgcn_mfma_f32_16x16x32_bf16(a11, b1, acc1[m][n], 0, 0, 0);
                acc2[m][n] = __builtin_amdgcn_mfma_f32_16x16x32_bf16(a20, b0, acc2[m][n], 0, 0, 0);
                acc2[m][n] = __builtin_amdgcn_mfma_f32_16x16x32_bf16(a21, b1, acc2[m][n], 0, 0, 0);
            }
        }
    }

    #pragma unroll
    for (int m = 0; m < 2; ++m)
        #pragma unroll
        for (int n = 0; n < 4; ++n)
            #pragma unroll
            for (int r = 0; r < 4; ++r) {
                int row = rb + wr * 32 + m * 16 + 4 * lg + r;
                int col = cb + wc * 64 + n * 16 + li;
                float v1 = fmaxf(acc1[m][n][r] + bo[col], 0.f);
                float v2 = fmaxf(acc2[m][n][r] + bo[col], 0.f);
                out[(size_t)z * (BB * NN * FF) + (size_t)row * FF + col] = v1 + v2 + 2.f * bo2[col];
            }
}

extern "C" void kernel_launch(void* const* d_in, const int* in_sizes, int n_in,
                              void* d_out, int out_size, void* d_ws, size_t ws_size,
                              hipStream_t stream) {
    const float* nfa  = (const float*)d_in[0];
    const float* nfb  = (const float*)d_in[1];
    const float* Aia  = (const float*)d_in[2];
    const float* Aib  = (const float*)d_in[3];
    const float* Ain  = (const float*)d_in[4];
    const float* W1   = (const float*)d_in[5];
    const float* b1   = (const float*)d_in[6];
    const float* W2   = (const float*)d_in[7];
    const float* b2   = (const float*)d_in[8];
    const float* W3   = (const float*)d_in[9];
    const float* b3   = (const float*)d_in[10];
    const float* Wia  = (const float*)d_in[11];
    const float* Wib  = (const float*)d_in[12];
    const float* Win  = (const float*)d_in[13];
    const float* Wout = (const float*)d_in[14];
    const float* bo   = (const float*)d_in[15];
    const float* bo2  = (const float*)d_in[16];

    u16* ws = (u16*)d_ws;
    float* out = (float*)d_out;

    prep_kernel<<<4096, 256, 0, stream>>>(nfa, nfb, Wout, Aia, Aib, Ain, W1, W2, W3, ws);
    proj_kernel<<<dim3(4, 32, 6), 256, 0, stream>>>(b1, b2, b3, ws);
    // AinT (prescaled bf16) overwrites the (now dead) Xa/Xb region
    tr_kernel<<<dim3(16, 16, 4), 256, 0, stream>>>(Ain, ws + XAOFF);
    attn_kernel<<<1024, 256, 0, stream>>>(ws + PBOFF, Wia, Wib, Win, ws + ADOFF, ws + XAOFF, ws + MSOFF);
    out_kernel<<<dim3(4, 64, 2), 256, 0, stream>>>(ws, bo, bo2, out);
}

// Round 5
// 133.703 us; speedup vs baseline: 2.2587x; 2.2587x over previous
//
#include <hip/hip_runtime.h>
#include <hip/hip_bf16.h>

// Problem constants
#define BB 4
#define NN 1024
#define FF 512
#define HH 8
#define KK 64
#define PSZ ((size_t)BB * HH * NN * KK)        // 2,097,152 elements

// ws layout (u16 units)
#define XAOFF 0u
#define XBOFF 2097152u
#define WTOFF 4194304u                          // Wt[3][512][512] bf16
#define WOOFF (WTOFF + 786432u)                 // Wout bf16 [512][512]
#define PBOFF (WOOFF + 262144u)                 // 6 projection buffers
#define MSOFF (PBOFF + 6u * 2097152u)           // 4 msgs buffers (bf16)
#define ADOFF (MSOFF + 4u * 2097152u)           // adj bf16 (prescaled by log2e) [3][4][1024][1024]
#define ADSZ  4194304u                          // per adj matrix (u16)
// AinT (bf16, prescaled, transposed A_inter) overwrites the dead Xa/Xb region

#define LOG2E 1.4426950408889634f
#define SHIFT2 34.624683f                       // 24 * log2e

typedef unsigned short u16;
typedef __attribute__((ext_vector_type(8))) short bf16x8;
typedef __attribute__((ext_vector_type(4))) short bf16x4;
typedef __attribute__((ext_vector_type(4))) float f32x4;
typedef __attribute__((ext_vector_type(8))) unsigned short ushort8;
typedef __attribute__((ext_vector_type(4))) unsigned short ushort4v;

#if defined(__has_builtin)
#if __has_builtin(__builtin_amdgcn_mfma_f32_16x16x16bf16_1k)
#define HAVE_MFMA16 1
#endif
#if __has_builtin(__builtin_amdgcn_global_load_lds)
#define HAVE_GLL 1
#endif
#endif
#ifndef HAVE_MFMA16
#define HAVE_MFMA16 0
#endif
#ifndef HAVE_GLL
#define HAVE_GLL 0
#endif

#if HAVE_GLL
#define GSTR 64
#else
#define GSTR 72
#endif

__device__ __forceinline__ u16 f2b(float x) {
    union { float f; unsigned u; } v; v.f = x;
    unsigned r = v.u + 0x7FFF + ((v.u >> 16) & 1);   // RNE
    return (u16)(r >> 16);
}
__device__ __forceinline__ float b2f(u16 x) {
    union { unsigned u; float f; } v; v.u = ((unsigned)x) << 16;
    return v.f;
}

// ---------------------------------------------------------------------------
// Kernel 0: merged prep (streaming converts) + wt (W transpose).
// ---------------------------------------------------------------------------
__global__ __launch_bounds__(256) void prep_kernel(
    const float* __restrict__ Xa, const float* __restrict__ Xb,
    const float* __restrict__ Wout,
    const float* __restrict__ Aia, const float* __restrict__ Aib,
    const float* __restrict__ Ain,
    const float* __restrict__ W1, const float* __restrict__ W2,
    const float* __restrict__ W3,
    u16* __restrict__ ws)
{
    __shared__ float T[64][65];
    const int bid = blockIdx.x;
    const int t = threadIdx.x;

    if (bid < 192) {
        const int j  = bid / 64;
        const int rem = bid & 63;
        const int h  = rem >> 3;
        const int f0 = (rem & 7) * 64;
        const float* Wj = j == 0 ? W1 : (j == 1 ? W2 : W3);
        const int tr = t >> 2, tc = (t & 3) * 16;
        const float* src = Wj + (size_t)h * FF * KK + (size_t)(f0 + tr) * KK + tc;
        #pragma unroll
        for (int jj = 0; jj < 4; ++jj) {
            float4 v = *(const float4*)(src + 4 * jj);
            T[tr][tc + 4 * jj + 0] = v.x;
            T[tr][tc + 4 * jj + 1] = v.y;
            T[tr][tc + 4 * jj + 2] = v.z;
            T[tr][tc + 4 * jj + 3] = v.w;
        }
        __syncthreads();
        ushort8 w0, w1;
        #pragma unroll
        for (int jj = 0; jj < 8; ++jj) {
            w0[jj] = f2b(T[tc + jj][tr]);
            w1[jj] = f2b(T[tc + 8 + jj][tr]);
        }
        u16* d = ws + WTOFF + (unsigned)j * 262144u + (unsigned)(h * 64 + tr) * 512u + f0 + tc;
        *(ushort8*)&d[0] = w0;
        *(ushort8*)&d[8] = w1;
        return;
    }

    const int NFLAT4 = (2097152 + 2097152 + 262144) / 4;   // 1,114,112
    const int NADJ4  = 3 * 1048576;                        // 3,145,728
    const int total  = NFLAT4 + NADJ4;
    const int nb = gridDim.x - 192;
    for (int idx = (bid - 192) * 256 + t; idx < total; idx += nb * 256) {
        if (idx < NFLAT4) {
            int e = idx * 4;
            const float* src; u16* dst;
            if (e < 2097152)      { src = Xa + e;             dst = ws + XAOFF + e; }
            else if (e < 4194304) { src = Xb + (e - 2097152); dst = ws + XBOFF + (e - 2097152); }
            else                  { src = Wout + (e - 4194304); dst = ws + WOOFF + (e - 4194304); }
            float4 v = *(const float4*)src;
            ushort4v w;
            w[0] = f2b(v.x); w[1] = f2b(v.y); w[2] = f2b(v.z); w[3] = f2b(v.w);
            *(ushort4v*)dst = w;
        } else {
            int r = idx - NFLAT4;
            int z = r >> 20;
            int rem = r & 1048575;
            const float* src = (z == 0 ? Aia : (z == 1 ? Aib : Ain)) + (size_t)rem * 4;
            float4 v = *(const float4*)src;
            ushort4v w;
            w[0] = f2b(v.x * LOG2E); w[1] = f2b(v.y * LOG2E);
            w[2] = f2b(v.z * LOG2E); w[3] = f2b(v.w * LOG2E);
            *(ushort4v*)(ws + ADOFF + (size_t)z * ADSZ + (size_t)rem * 4) = w;
        }
    }
}

// ---------------------------------------------------------------------------
// Kernel 0b: AinT[b][c][r] = bf16(Ain[b][r][c] * log2e); into dead Xa/Xb region.
// ---------------------------------------------------------------------------
__global__ __launch_bounds__(256) void tr_kernel(const float* __restrict__ A, u16* __restrict__ dst)
{
    const int b = blockIdx.z;
    const int r0 = blockIdx.y * 64, c0 = blockIdx.x * 64;
    __shared__ float T[64][65];
    const int t = threadIdx.x;
    const int tr = t >> 2, tc = (t & 3) * 16;
    const float* src = A + ((size_t)b * NN + r0 + tr) * NN + c0 + tc;
    #pragma unroll
    for (int j = 0; j < 4; ++j) {
        float4 v = *(const float4*)(src + 4 * j);
        T[tr][tc + 4 * j + 0] = v.x;
        T[tr][tc + 4 * j + 1] = v.y;
        T[tr][tc + 4 * j + 2] = v.z;
        T[tr][tc + 4 * j + 3] = v.w;
    }
    __syncthreads();
    ushort8 w0, w1;
    #pragma unroll
    for (int j = 0; j < 8; ++j) {
        w0[j] = f2b(T[tc + j][tr] * LOG2E);
        w1[j] = f2b(T[tc + 8 + j][tr] * LOG2E);
    }
    u16* d = dst + ((size_t)b * NN + c0 + tr) * NN + r0 + tc;
    *(ushort8*)&d[0] = w0;
    *(ushort8*)&d[8] = w1;
}

// ---------------------------------------------------------------------------
// Kernel 1: MFMA projections. z = src*3 + pj. 128x128 tile, 4 waves (2x2).
// ---------------------------------------------------------------------------
__global__ __launch_bounds__(256) void proj_kernel(
    const float* __restrict__ b1v, const float* __restrict__ b2v,
    const float* __restrict__ b3v,
    u16* __restrict__ ws)
{
    const int z  = blockIdx.z;
    const int src = z / 3, pj = z % 3;
    const u16* X  = ws + (src ? XBOFF : XAOFF);
    const u16* Wt = ws + WTOFF + (unsigned)pj * 262144u;
    const float* bias = pj == 0 ? b1v : (pj == 1 ? b2v : b3v);
    u16* P = ws + PBOFF + (size_t)z * PSZ;

    const int rb = blockIdx.y * 128;
    const int cb = blockIdx.x * 128;
    const int t  = threadIdx.x;
    const int lane = t & 63, wave = t >> 6;
    const int lg = lane >> 4, li = lane & 15;
    const int wr = wave >> 1, wc = wave & 1;

    __shared__ u16 As[128 * GSTR];
    __shared__ u16 Bs[128 * GSTR];

    f32x4 acc[4][4];
    #pragma unroll
    for (int m = 0; m < 4; ++m)
        #pragma unroll
        for (int n = 0; n < 4; ++n) acc[m][n] = (f32x4){0.f, 0.f, 0.f, 0.f};

#if !HAVE_GLL
    const int srow = t >> 1, sf0 = (t & 1) * 32;
#endif

    for (int fb = 0; fb < FF; fb += 64) {
        __syncthreads();
#if HAVE_GLL
        {
            const int gr = wave * 32 + (lane >> 3);
            const int gc = (lane & 7) * 8;
            #pragma unroll
            for (int i = 0; i < 4; ++i) {
                __builtin_amdgcn_global_load_lds(
                    (const unsigned int*)&X[(size_t)(rb + gr + 8 * i) * FF + fb + gc],
                    (unsigned int*)&As[(wave * 32 + 8 * i) * GSTR], 16, 0, 0);
                __builtin_amdgcn_global_load_lds(
                    (const unsigned int*)&Wt[(size_t)(cb + gr + 8 * i) * FF + fb + gc],
                    (unsigned int*)&Bs[(wave * 32 + 8 * i) * GSTR], 16, 0, 0);
            }
        }
#else
        #pragma unroll
        for (int s = 0; s < 4; ++s) {
            *(ushort8*)&As[srow * GSTR + sf0 + 8 * s] =
                *(const ushort8*)&X[(size_t)(rb + srow) * FF + fb + sf0 + 8 * s];
            *(ushort8*)&Bs[srow * GSTR + sf0 + 8 * s] =
                *(const ushort8*)&Wt[(size_t)(cb + srow) * FF + fb + sf0 + 8 * s];
        }
#endif
        __syncthreads();

        bf16x8 af[4][2], bf[4][2];
        #pragma unroll
        for (int m = 0; m < 4; ++m) {
            af[m][0] = *(const bf16x8*)&As[(wr * 64 + m * 16 + li) * GSTR + 8 * lg];
            af[m][1] = *(const bf16x8*)&As[(wr * 64 + m * 16 + li) * GSTR + 8 * lg + 32];
        }
        #pragma unroll
        for (int n = 0; n < 4; ++n) {
            bf[n][0] = *(const bf16x8*)&Bs[(wc * 64 + n * 16 + li) * GSTR + 8 * lg];
            bf[n][1] = *(const bf16x8*)&Bs[(wc * 64 + n * 16 + li) * GSTR + 8 * lg + 32];
        }
        #pragma unroll
        for (int m = 0; m < 4; ++m)
            #pragma unroll
            for (int n = 0; n < 4; ++n) {
                acc[m][n] = __builtin_amdgcn_mfma_f32_16x16x32_bf16(af[m][0], bf[n][0], acc[m][n], 0, 0, 0);
                acc[m][n] = __builtin_amdgcn_mfma_f32_16x16x32_bf16(af[m][1], bf[n][1], acc[m][n], 0, 0, 0);
            }
    }

    if (pj != 2) {
        #pragma unroll
        for (int m = 0; m < 4; ++m)
            #pragma unroll
            for (int n = 0; n < 4; ++n)
                #pragma unroll
                for (int r = 0; r < 4; ++r) {
                    int row = rb + wr * 64 + m * 16 + 4 * lg + r;
                    int col = cb + wc * 64 + n * 16 + li;
                    int b_ = row >> 10, n_ = row & 1023;
                    int h = col >> 6, k = col & 63;
                    P[((size_t)(b_ * HH + h) * NN + n_) * KK + k] = f2b(acc[m][n][r] + bias[col]);
                }
    } else {
        #pragma unroll
        for (int m = 0; m < 4; ++m)
            #pragma unroll
            for (int n = 0; n < 4; ++n) {
                int col = cb + wc * 64 + n * 16 + li;
                int h = col >> 6, k = col & 63;
                int row0 = rb + wr * 64 + m * 16 + 4 * lg;
                int b_ = row0 >> 10, n0 = row0 & 1023;
                float bsv = bias[col];
                ushort4v w;
                #pragma unroll
                for (int r = 0; r < 4; ++r) w[r] = f2b(acc[m][n][r] + bsv);
                *(ushort4v*)&P[((size_t)(b_ * HH + h) * KK + k) * NN + n0] = w;
            }
    }
}

// ---------------------------------------------------------------------------
// Kernel 2: MFMA flash attention — round-0 known-good structure with T2
// XOR-swizzled LDS tiles (stride 72 -> 64 u16 + col^((row&7)<<3)).
// Rationale (r4 post-mortem): r0's stride-144B layout puts 8 lanes of every
// b128 fragment read on the same 4-bank group (~4-way serialize; 9.2M
// conflict cycles = 22% of runtime). With power-of-2 stride the row term
// vanishes from the bank index (128B = 32 banks), so bank = col16^(row&7)
// alone; verified for all 9 access patterns: 64 lanes spread exactly
// 8-per-4-bank-group = zero conflict. Structure, barriers, instruction
// counts unchanged from r0. LDS 36.8KB -> 32KB.
// ---------------------------------------------------------------------------
#define SWU(ROW, CU) (((ROW) << 6) + ((CU) ^ (((ROW) & 7) << 3)))

__global__ __launch_bounds__(256, 4) void attn_kernel(
    const u16* __restrict__ Pbase,
    const float* __restrict__ Wia, const float* __restrict__ Wib, const float* __restrict__ Win,
    const u16* __restrict__ AD, const u16* __restrict__ AinT,
    u16* __restrict__ msgs)
{
    // hw flat id -> logical (q, bh, agg); 1024 = 8 XCD chunks x 128
    const int flat = blockIdx.x;
    const int lf   = (flat & 7) * 128 + (flat >> 3);
    const int qb   = (lf & 7) * 128;
    const int bh   = (lf >> 3) & 31;
    const int agg  = lf >> 8;
    const int b = bh >> 3, h = bh & 7;
    const int t = threadIdx.x;
    const int lane = t & 63, wave = t >> 6;
    const int lg = lane >> 4, li = lane & 15;

    const u16 *Qp, *Kp, *Vp, *adj; const float* ew;
    switch (agg) {
      case 0: Qp = Pbase;         ew = Wia; Kp = Pbase + 1*PSZ; Vp = Pbase + 2*PSZ; adj = AD;          break;
      case 1: Qp = Pbase + 3*PSZ; ew = Wib; Kp = Pbase + 4*PSZ; Vp = Pbase + 5*PSZ; adj = AD + 1*ADSZ; break;
      case 2: Qp = Pbase;         ew = Win; Kp = Pbase + 4*PSZ; Vp = Pbase + 2*PSZ; adj = AD + 2*ADSZ; break;
      default:Qp = Pbase + 3*PSZ; ew = Win; Kp = Pbase + 1*PSZ; Vp = Pbase + 5*PSZ; adj = AinT;        break;
    }
    const size_t bhoff = (size_t)(b * HH + h) * NN * KK;
    const u16* Qbh  = Qp + bhoff;       // [n][k] bf16
    const u16* Kbh  = Kp + bhoff;       // [n][k] bf16
    const u16* Vbh  = Vp + bhoff;       // [k][n] bf16 (pre-transposed)
    const u16* adjb = adj + (size_t)b * NN * NN;   // mask[q][m] bf16 (prescaled)

    __shared__ u16 Qa[128 * 64];        // Q-out (preamble) -> adj (loop); swizzled
    __shared__ u16 Kt[64 * 64];         // F1-half (preamble) -> K (loop); swizzled
    __shared__ u16 Vt[64 * 64];         // ewT (preamble) -> V (loop); swizzled

    const int sr  = t >> 2;             // 0..63
    const int sc  = (t & 3) * 16;
    const int sr2 = t >> 1;             // 0..127 (adj staging)
    const int sc2 = (t & 1) * 32;

    // ---------------- preamble: Q = F1 @ ew for 128 rows ----------------
    #pragma unroll
    for (int j = 0; j < 16; ++j)        // Vt[l][k'] = ew[k'][l]
        Vt[SWU(sc + j, sr)] = f2b(ew[sr * 64 + sc + j]);

    #pragma unroll
    for (int p = 0; p < 2; ++p) {
        __syncthreads();
        {
            const ushort8* src = (const ushort8*)&Qbh[(size_t)(qb + p * 64 + sr) * KK + sc];
            *(ushort8*)&Kt[SWU(sr, sc)]     = src[0];
            *(ushort8*)&Kt[SWU(sr, sc + 8)] = src[1];
        }
        __syncthreads();
        bf16x8 a0 = *(const bf16x8*)&Kt[SWU(wave * 16 + li, 8 * lg)];
        bf16x8 a1 = *(const bf16x8*)&Kt[SWU(wave * 16 + li, 8 * lg + 32)];
        #pragma unroll
        for (int t_ = 0; t_ < 4; ++t_) {
            bf16x8 b0 = *(const bf16x8*)&Vt[SWU(li + 16 * t_, 8 * lg)];
            bf16x8 b1 = *(const bf16x8*)&Vt[SWU(li + 16 * t_, 8 * lg + 32)];
            f32x4 q = {0.f, 0.f, 0.f, 0.f};
            q = __builtin_amdgcn_mfma_f32_16x16x32_bf16(a0, b0, q, 0, 0, 0);
            q = __builtin_amdgcn_mfma_f32_16x16x32_bf16(a1, b1, q, 0, 0, 0);
            #pragma unroll
            for (int r = 0; r < 4; ++r)
                Qa[SWU(p * 64 + wave * 16 + 4 * lg + r, li + 16 * t_)] = f2b(q[r]);
        }
    }
    __syncthreads();
    bf16x8 qB[2][2];
    #pragma unroll
    for (int u = 0; u < 2; ++u)
        #pragma unroll
        for (int c = 0; c < 2; ++c)
            qB[u][c] = *(const bf16x8*)&Qa[SWU(wave * 32 + u * 16 + li, 32 * c + 8 * lg)];
    __syncthreads();                    // Qa free for adj staging

    f32x4 oacc[2][4];
    #pragma unroll
    for (int u = 0; u < 2; ++u)
        #pragma unroll
        for (int f_ = 0; f_ < 4; ++f_) oacc[u][f_] = (f32x4){0.f, 0.f, 0.f, 0.f};
    float lsum[2] = {0.f, 0.f};

    for (int mt = 0; mt < 16; ++mt) {
        const int mb = mt * 64;
        // ---- stage K, V (64x64), adj (128x64) ----
        {
            const ushort8* ks = (const ushort8*)&Kbh[(size_t)(mb + sr) * KK + sc];
            *(ushort8*)&Kt[SWU(sr, sc)]     = ks[0];
            *(ushort8*)&Kt[SWU(sr, sc + 8)] = ks[1];
            const ushort8* vs = (const ushort8*)&Vbh[(size_t)sr * NN + mb + sc];
            *(ushort8*)&Vt[SWU(sr, sc)]     = vs[0];
            *(ushort8*)&Vt[SWU(sr, sc + 8)] = vs[1];
            const u16* ap = &adjb[(size_t)(qb + sr2) * NN + mb + sc2];
            #pragma unroll
            for (int s = 0; s < 4; ++s)
                *(ushort8*)&Qa[SWU(sr2, sc2 + 8 * s)] = *(const ushort8*)&ap[8 * s];
        }
        __syncthreads();

        // ---- adj fragments (b64, wave-local rows) ----
        ushort4v adv[2][4];
        #pragma unroll
        for (int u = 0; u < 2; ++u)
            #pragma unroll
            for (int t_ = 0; t_ < 4; ++t_)
                adv[u][t_] = *(const ushort4v*)&Qa[SWU(wave * 32 + u * 16 + li, 16 * t_ + 4 * lg)];

        // ---- S^T + masked exp2 (fixed shift; exact) + cvt_pk pack ----
#if HAVE_MFMA16
        bf16x4 pa[2][4];
#endif
        #pragma unroll
        for (int t_ = 0; t_ < 4; ++t_) {
            bf16x8 kb0 = *(const bf16x8*)&Kt[SWU(li + 16 * t_, 8 * lg)];
            bf16x8 kb1 = *(const bf16x8*)&Kt[SWU(li + 16 * t_, 8 * lg + 32)];
            #pragma unroll
            for (int u = 0; u < 2; ++u) {
                f32x4 s = {0.f, 0.f, 0.f, 0.f};
                __builtin_amdgcn_s_setprio(1);
                s = __builtin_amdgcn_mfma_f32_16x16x32_bf16(kb0, qB[u][0], s, 0, 0, 0);
                s = __builtin_amdgcn_mfma_f32_16x16x32_bf16(kb1, qB[u][1], s, 0, 0, 0);
                __builtin_amdgcn_s_setprio(0);
                float p0 = __builtin_amdgcn_exp2f(fmaf(s[0], b2f(adv[u][t_][0]), -SHIFT2));
                float p1 = __builtin_amdgcn_exp2f(fmaf(s[1], b2f(adv[u][t_][1]), -SHIFT2));
                float p2 = __builtin_amdgcn_exp2f(fmaf(s[2], b2f(adv[u][t_][2]), -SHIFT2));
                float p3 = __builtin_amdgcn_exp2f(fmaf(s[3], b2f(adv[u][t_][3]), -SHIFT2));
                lsum[u] += (p0 + p1) + (p2 + p3);
                unsigned w0, w1;
                asm("v_cvt_pk_bf16_f32 %0, %1, %2" : "=v"(w0) : "v"(p0), "v"(p1));
                asm("v_cvt_pk_bf16_f32 %0, %1, %2" : "=v"(w1) : "v"(p2), "v"(p3));
#if HAVE_MFMA16
                union { uint2 u2; bf16x4 v; } pk;
                pk.u2.x = w0; pk.u2.y = w1;
                pa[u][t_] = pk.v;
#else
                uint2 pd; pd.x = w0; pd.y = w1;
                *(uint2*)&Qa[SWU(wave * 32 + u * 16 + li, 16 * t_ + 4 * lg)] = pd;
#endif
            }
        }

#if HAVE_MFMA16
        // ---- O += P @ V straight from registers (K=16 MFMA, b64 V-frags) ----
        __builtin_amdgcn_s_setprio(1);
        #pragma unroll
        for (int f_ = 0; f_ < 4; ++f_) {
            #pragma unroll
            for (int t_ = 0; t_ < 4; ++t_) {
                bf16x4 vb = *(const bf16x4*)&Vt[SWU(li + 16 * f_, 16 * t_ + 4 * lg)];
                #pragma unroll
                for (int u = 0; u < 2; ++u)
                    oacc[u][f_] = __builtin_amdgcn_mfma_f32_16x16x16bf16_1k(pa[u][t_], vb, oacc[u][f_], 0, 0, 0);
            }
        }
        __builtin_amdgcn_s_setprio(0);
#else
        {
            bf16x8 pA[2][2];
            #pragma unroll
            for (int u = 0; u < 2; ++u) {
                pA[u][0] = *(const bf16x8*)&Qa[SWU(wave * 32 + u * 16 + li, 8 * lg)];
                pA[u][1] = *(const bf16x8*)&Qa[SWU(wave * 32 + u * 16 + li, 8 * lg + 32)];
            }
            #pragma unroll
            for (int f_ = 0; f_ < 4; ++f_) {
                bf16x8 vb0 = *(const bf16x8*)&Vt[SWU(li + 16 * f_, 8 * lg)];
                bf16x8 vb1 = *(const bf16x8*)&Vt[SWU(li + 16 * f_, 8 * lg + 32)];
                #pragma unroll
                for (int u = 0; u < 2; ++u) {
                    oacc[u][f_] = __builtin_amdgcn_mfma_f32_16x16x32_bf16(pA[u][0], vb0, oacc[u][f_], 0, 0, 0);
                    oacc[u][f_] = __builtin_amdgcn_mfma_f32_16x16x32_bf16(pA[u][1], vb1, oacc[u][f_], 0, 0, 0);
                }
            }
        }
#endif
        __syncthreads();
    }

    // ---- epilogue: reduce l over 16-lane groups, normalize, write msgs ----
    #pragma unroll
    for (int u = 0; u < 2; ++u) {
        lsum[u] += __shfl_xor(lsum[u], 16);
        lsum[u] += __shfl_xor(lsum[u], 32);
    }
    #pragma unroll
    for (int u = 0; u < 2; ++u)
        #pragma unroll
        for (int r = 0; r < 4; ++r) {
            float inv = 1.f / __shfl(lsum[u], 4 * lg + r);
            int row = qb + wave * 32 + u * 16 + 4 * lg + r;
            u16* dst = msgs + (size_t)agg * PSZ + ((size_t)b * NN + row) * (HH * KK) + h * KK;
            #pragma unroll
            for (int f_ = 0; f_ < 4; ++f_)
                dst[li + 16 * f_] = f2b(oacc[u][f_][r] * inv);
        }
}

// ---------------------------------------------------------------------------
// Kernel 3: MFMA output projection, 64x128 tile (512 blocks = 2/CU).
// ---------------------------------------------------------------------------
__global__ __launch_bounds__(256) void out_kernel(
    const u16* __restrict__ ws,
    const float* __restrict__ bo, const float* __restrict__ bo2,
    float* __restrict__ out)
{
    const int z  = blockIdx.z;
    const u16* M1 = ws + MSOFF + (size_t)z * PSZ;
    const u16* M2 = ws + MSOFF + (size_t)(2 + z) * PSZ;
    const u16* Wb = ws + WOOFF;
    const int rb = blockIdx.y * 64;
    const int cb = blockIdx.x * 128;
    const int t  = threadIdx.x;
    const int lane = t & 63, wave = t >> 6;
    const int lg = lane >> 4, li = lane & 15;
    const int wr = wave >> 1, wc = wave & 1;

    __shared__ u16 A1s[64 * GSTR];
    __shared__ u16 A2s[64 * GSTR];
    __shared__ u16 Bs[128 * GSTR];

    f32x4 acc1[2][4], acc2[2][4];
    #pragma unroll
    for (int m = 0; m < 2; ++m)
        #pragma unroll
        for (int n = 0; n < 4; ++n) {
            acc1[m][n] = (f32x4){0.f, 0.f, 0.f, 0.f};
            acc2[m][n] = (f32x4){0.f, 0.f, 0.f, 0.f};
        }

    for (int fb = 0; fb < FF; fb += 64) {
        __syncthreads();
#if HAVE_GLL
        {
            const int lr = lane >> 3;
            const int gc = (lane & 7) * 8;
            #pragma unroll
            for (int i = 0; i < 2; ++i) {
                __builtin_amdgcn_global_load_lds(
                    (const unsigned int*)&M1[(size_t)(rb + wave * 16 + 8 * i + lr) * FF + fb + gc],
                    (unsigned int*)&A1s[(wave * 16 + 8 * i) * GSTR], 16, 0, 0);
                __builtin_amdgcn_global_load_lds(
                    (const unsigned int*)&M2[(size_t)(rb + wave * 16 + 8 * i + lr) * FF + fb + gc],
                    (unsigned int*)&A2s[(wave * 16 + 8 * i) * GSTR], 16, 0, 0);
            }
            #pragma unroll
            for (int i = 0; i < 4; ++i) {
                __builtin_amdgcn_global_load_lds(
                    (const unsigned int*)&Wb[(size_t)(cb + wave * 32 + 8 * i + lr) * FF + fb + gc],
                    (unsigned int*)&Bs[(wave * 32 + 8 * i) * GSTR], 16, 0, 0);
            }
        }
#else
        {
            int ar = t >> 2, ac = (t & 3) * 16;
            *(ushort8*)&A1s[ar * GSTR + ac]     = *(const ushort8*)&M1[(size_t)(rb + ar) * FF + fb + ac];
            *(ushort8*)&A1s[ar * GSTR + ac + 8] = *(const ushort8*)&M1[(size_t)(rb + ar) * FF + fb + ac + 8];
            *(ushort8*)&A2s[ar * GSTR + ac]     = *(const ushort8*)&M2[(size_t)(rb + ar) * FF + fb + ac];
            *(ushort8*)&A2s[ar * GSTR + ac + 8] = *(const ushort8*)&M2[(size_t)(rb + ar) * FF + fb + ac + 8];
            int br = t >> 1, bc = (t & 1) * 32;
            #pragma unroll
            for (int s = 0; s < 4; ++s)
                *(ushort8*)&Bs[br * GSTR + bc + 8 * s] =
                    *(const ushort8*)&Wb[(size_t)(cb + br) * FF + fb + bc + 8 * s];
        }
#endif
        __syncthreads();

        #pragma unroll
        for (int m = 0; m < 2; ++m) {
            bf16x8 a10 = *(const bf16x8*)&A1s[(wr * 32 + m * 16 + li) * GSTR + 8 * lg];
            bf16x8 a11 = *(const bf16x8*)&A1s[(wr * 32 + m * 16 + li) * GSTR + 8 * lg + 32];
            bf16x8 a20 = *(const bf16x8*)&A2s[(wr * 32 + m * 16 + li) * GSTR + 8 * lg];
            bf16x8 a21 = *(const bf16x8*)&A2s[(wr * 32 + m * 16 + li) * GSTR + 8 * lg + 32];
            #pragma unroll
            for (int n = 0; n < 4; ++n) {
                bf16x8 b0 = *(const bf16x8*)&Bs[(wc * 64 + n * 16 + li) * GSTR + 8 * lg];
                bf16x8 b1 = *(const bf16x8*)&Bs[(wc * 64 + n * 16 + li) * GSTR + 8 * lg + 32];
                acc1[m][n] = __builtin_amdgcn_mfma_f32_16x16x32_bf16(a10, b0, acc1[m][n], 0, 0, 0);
                acc1[m][n] = __builtin_amdgcn_mfma_f32_16x16x32_bf16(a11, b1, acc1[m][n], 0, 0, 0);
                acc2[m][n] = __builtin_amdgcn_mfma_f32_16x16x32_bf16(a20, b0, acc2[m][n], 0, 0, 0);
                acc2[m][n] = __builtin_amdgcn_mfma_f32_16x16x32_bf16(a21, b1, acc2[m][n], 0, 0, 0);
            }
        }
    }

    #pragma unroll
    for (int m = 0; m < 2; ++m)
        #pragma unroll
        for (int n = 0; n < 4; ++n)
            #pragma unroll
            for (int r = 0; r < 4; ++r) {
                int row = rb + wr * 32 + m * 16 + 4 * lg + r;
                int col = cb + wc * 64 + n * 16 + li;
                float v1 = fmaxf(acc1[m][n][r] + bo[col], 0.f);
                float v2 = fmaxf(acc2[m][n][r] + bo[col], 0.f);
                out[(size_t)z * (BB * NN * FF) + (size_t)row * FF + col] = v1 + v2 + 2.f * bo2[col];
            }
}

extern "C" void kernel_launch(void* const* d_in, const int* in_sizes, int n_in,
                              void* d_out, int out_size, void* d_ws, size_t ws_size,
                              hipStream_t stream) {
    const float* nfa  = (const float*)d_in[0];
    const float* nfb  = (const float*)d_in[1];
    const float* Aia  = (const float*)d_in[2];
    const float* Aib  = (const float*)d_in[3];
    const float* Ain  = (const float*)d_in[4];
    const float* W1   = (const float*)d_in[5];
    const float* b1   = (const float*)d_in[6];
    const float* W2   = (const float*)d_in[7];
    const float* b2   = (const float*)d_in[8];
    const float* W3   = (const float*)d_in[9];
    const float* b3   = (const float*)d_in[10];
    const float* Wia  = (const float*)d_in[11];
    const float* Wib  = (const float*)d_in[12];
    const float* Win  = (const float*)d_in[13];
    const float* Wout = (const float*)d_in[14];
    const float* bo   = (const float*)d_in[15];
    const float* bo2  = (const float*)d_in[16];

    u16* ws = (u16*)d_ws;
    float* out = (float*)d_out;

    prep_kernel<<<4096, 256, 0, stream>>>(nfa, nfb, Wout, Aia, Aib, Ain, W1, W2, W3, ws);
    proj_kernel<<<dim3(4, 32, 6), 256, 0, stream>>>(b1, b2, b3, ws);
    // AinT (prescaled bf16) overwrites the (now dead) Xa/Xb region
    tr_kernel<<<dim3(16, 16, 4), 256, 0, stream>>>(Ain, ws + XAOFF);
    attn_kernel<<<1024, 256, 0, stream>>>(ws + PBOFF, Wia, Wib, Win, ws + ADOFF, ws + XAOFF, ws + MSOFF);
    out_kernel<<<dim3(4, 64, 2), 256, 0, stream>>>(ws, bo, bo2, out);
}

// Round 6
// 132.993 us; speedup vs baseline: 2.2707x; 1.0053x over previous
//
#include <hip/hip_runtime.h>
#include <hip/hip_bf16.h>

// Problem constants
#define BB 4
#define NN 1024
#define FF 512
#define HH 8
#define KK 64
#define PSZ ((size_t)BB * HH * NN * KK)        // 2,097,152 elements

// ws layout (u16 units)
#define XAOFF 0u
#define XBOFF 2097152u
#define WTOFF 4194304u                          // Wt[3][512][512] bf16
#define WOOFF (WTOFF + 786432u)                 // Wout bf16 [512][512]
#define PBOFF (WOOFF + 262144u)                 // 6 projection buffers
#define MSOFF (PBOFF + 6u * 2097152u)           // 4 msgs buffers (bf16)
#define ADOFF (MSOFF + 4u * 2097152u)           // PERMUTED adj bf16 (prescaled), aggs 0-2
#define ADSZ  4194304u                          // per agg (u16)
// agg3 (AinT) permuted adj lives in the dead Xa/Xb region (XAOFF, 4M u16)

#define LOG2E 1.4426950408889634f
#define SHIFT2 34.624683f                       // 24 * log2e

typedef unsigned short u16;
typedef __attribute__((ext_vector_type(8))) short bf16x8;
typedef __attribute__((ext_vector_type(4))) short bf16x4;
typedef __attribute__((ext_vector_type(4))) float f32x4;
typedef __attribute__((ext_vector_type(8))) unsigned short ushort8;
typedef __attribute__((ext_vector_type(4))) unsigned short ushort4v;

#if defined(__has_builtin)
#if __has_builtin(__builtin_amdgcn_mfma_f32_16x16x16bf16_1k)
#define HAVE_MFMA16 1
#endif
#if __has_builtin(__builtin_amdgcn_global_load_lds)
#define HAVE_GLL 1
#endif
#endif
#ifndef HAVE_MFMA16
#define HAVE_MFMA16 0
#endif
#ifndef HAVE_GLL
#define HAVE_GLL 0
#endif

#if HAVE_GLL
#define GSTR 64
#else
#define GSTR 72
#endif

__device__ __forceinline__ u16 f2b(float x) {
    union { float f; unsigned u; } v; v.f = x;
    unsigned r = v.u + 0x7FFF + ((v.u >> 16) & 1);   // RNE
    return (u16)(r >> 16);
}
__device__ __forceinline__ float b2f(u16 x) {
    union { unsigned u; float f; } v; v.u = ((unsigned)x) << 16;
    return v.f;
}

// ---------------------------------------------------------------------------
// Kernel 0: prep — W transpose + streaming converts of Xa/Xb/Wout.
// (adj conversion moved to perm/permt kernels below.)
// ---------------------------------------------------------------------------
__global__ __launch_bounds__(256) void prep_kernel(
    const float* __restrict__ Xa, const float* __restrict__ Xb,
    const float* __restrict__ Wout,
    const float* __restrict__ W1, const float* __restrict__ W2,
    const float* __restrict__ W3,
    u16* __restrict__ ws)
{
    __shared__ float T[64][65];
    const int bid = blockIdx.x;
    const int t = threadIdx.x;

    if (bid < 192) {
        const int j  = bid / 64;
        const int rem = bid & 63;
        const int h  = rem >> 3;
        const int f0 = (rem & 7) * 64;
        const float* Wj = j == 0 ? W1 : (j == 1 ? W2 : W3);
        const int tr = t >> 2, tc = (t & 3) * 16;
        const float* src = Wj + (size_t)h * FF * KK + (size_t)(f0 + tr) * KK + tc;
        #pragma unroll
        for (int jj = 0; jj < 4; ++jj) {
            float4 v = *(const float4*)(src + 4 * jj);
            T[tr][tc + 4 * jj + 0] = v.x;
            T[tr][tc + 4 * jj + 1] = v.y;
            T[tr][tc + 4 * jj + 2] = v.z;
            T[tr][tc + 4 * jj + 3] = v.w;
        }
        __syncthreads();
        ushort8 w0, w1;
        #pragma unroll
        for (int jj = 0; jj < 8; ++jj) {
            w0[jj] = f2b(T[tc + jj][tr]);
            w1[jj] = f2b(T[tc + 8 + jj][tr]);
        }
        u16* d = ws + WTOFF + (unsigned)j * 262144u + (unsigned)(h * 64 + tr) * 512u + f0 + tc;
        *(ushort8*)&d[0] = w0;
        *(ushort8*)&d[8] = w1;
        return;
    }

    const int NFLAT4 = (2097152 + 2097152 + 262144) / 4;   // 1,114,112
    const int nb = gridDim.x - 192;
    for (int idx = (bid - 192) * 256 + t; idx < NFLAT4; idx += nb * 256) {
        int e = idx * 4;
        const float* src; u16* dst;
        if (e < 2097152)      { src = Xa + e;             dst = ws + XAOFF + e; }
        else if (e < 4194304) { src = Xb + (e - 2097152); dst = ws + XBOFF + (e - 2097152); }
        else                  { src = Wout + (e - 4194304); dst = ws + WOOFF + (e - 4194304); }
        float4 v = *(const float4*)src;
        ushort4v w;
        w[0] = f2b(v.x); w[1] = f2b(v.y); w[2] = f2b(v.z); w[3] = f2b(v.w);
        *(ushort4v*)dst = w;
    }
}

// ---------------------------------------------------------------------------
// Kernel 0a: adj permute for aggs 0-2 (row order preserved).
// Output layout per (agg,b): [qblk8][mt16][wave4][u2][t_4][lane64*4] bf16,
// prescaled by log2e. A wave's fragment read adv[u][t_] becomes one
// contiguous 512B b64 load. Element (q,m): q = qblk*128+wave*32+u*16+li,
// m = mt*64 + t_*16 + lg*4 + e, lane = lg*16+li.
// ---------------------------------------------------------------------------
__global__ __launch_bounds__(256) void perm_kernel(
    const float* __restrict__ Aia, const float* __restrict__ Aib,
    const float* __restrict__ Ain, u16* __restrict__ ws)
{
    const int z = blockIdx.z;
    const int b = blockIdx.y;
    const int x = blockIdx.x;               // qblk*16 + mt
    const int qblk = x >> 4, mt = x & 15;
    const float* A = (z == 0 ? Aia : (z == 1 ? Aib : Ain)) + ((size_t)b << 20);
    u16* out = ws + ADOFF + (size_t)z * ADSZ + ((size_t)b << 20) + (size_t)x * 8192;
    const int t = threadIdx.x;
    const int w = t >> 6, l = t & 63;
    const int lg = l >> 4, li = l & 15;
    #pragma unroll
    for (int u = 0; u < 2; ++u)
        #pragma unroll
        for (int t_ = 0; t_ < 4; ++t_) {
            const int row = qblk * 128 + w * 32 + u * 16 + li;
            const int col = mt * 64 + t_ * 16 + lg * 4;
            float4 v = *(const float4*)&A[(size_t)row * NN + col];
            ushort4v o;
            o[0] = f2b(v.x * LOG2E); o[1] = f2b(v.y * LOG2E);
            o[2] = f2b(v.z * LOG2E); o[3] = f2b(v.w * LOG2E);
            *(ushort4v*)&out[(size_t)(w * 8 + u * 4 + t_) * 256 + l * 4] = o;
        }
}

// ---------------------------------------------------------------------------
// Kernel 0b: adj permute for agg 3 (transposed A_inter), via LDS tile.
// adjT[q][m] = Ain[b][m][q]; same permuted output layout, into XAOFF region.
// Runs AFTER proj (overwrites the bf16 X buffers).
// ---------------------------------------------------------------------------
__global__ __launch_bounds__(256) void permt_kernel(const float* __restrict__ Ain, u16* __restrict__ dst)
{
    const int b = blockIdx.y;
    const int x = blockIdx.x;               // qblk*16 + mt
    const int qblk = x >> 4, mt = x & 15;
    __shared__ float T[64][132];
    const int t = threadIdx.x;
    const int tr = t >> 2, tc = (t & 3) * 32;
    const float* src = Ain + ((size_t)b << 20) + (size_t)(mt * 64 + tr) * NN + qblk * 128 + tc;
    #pragma unroll
    for (int j = 0; j < 8; ++j) {
        float4 v = *(const float4*)(src + 4 * j);
        T[tr][tc + 4 * j + 0] = v.x;
        T[tr][tc + 4 * j + 1] = v.y;
        T[tr][tc + 4 * j + 2] = v.z;
        T[tr][tc + 4 * j + 3] = v.w;
    }
    __syncthreads();
    const int w = t >> 6, l = t & 63;
    const int lg = l >> 4, li = l & 15;
    u16* out = dst + ((size_t)b << 20) + (size_t)x * 8192;
    #pragma unroll
    for (int u = 0; u < 2; ++u)
        #pragma unroll
        for (int t_ = 0; t_ < 4; ++t_) {
            ushort4v o;
            #pragma unroll
            for (int e = 0; e < 4; ++e)
                o[e] = f2b(T[t_ * 16 + lg * 4 + e][w * 32 + u * 16 + li] * LOG2E);
            *(ushort4v*)&out[(size_t)(w * 8 + u * 4 + t_) * 256 + l * 4] = o;
        }
}

// ---------------------------------------------------------------------------
// Kernel 1: MFMA projections. z = src*3 + pj. 128x128 tile, 4 waves (2x2).
// ---------------------------------------------------------------------------
__global__ __launch_bounds__(256) void proj_kernel(
    const float* __restrict__ b1v, const float* __restrict__ b2v,
    const float* __restrict__ b3v,
    u16* __restrict__ ws)
{
    const int z  = blockIdx.z;
    const int src = z / 3, pj = z % 3;
    const u16* X  = ws + (src ? XBOFF : XAOFF);
    const u16* Wt = ws + WTOFF + (unsigned)pj * 262144u;
    const float* bias = pj == 0 ? b1v : (pj == 1 ? b2v : b3v);
    u16* P = ws + PBOFF + (size_t)z * PSZ;

    const int rb = blockIdx.y * 128;
    const int cb = blockIdx.x * 128;
    const int t  = threadIdx.x;
    const int lane = t & 63, wave = t >> 6;
    const int lg = lane >> 4, li = lane & 15;
    const int wr = wave >> 1, wc = wave & 1;

    __shared__ u16 As[128 * GSTR];
    __shared__ u16 Bs[128 * GSTR];

    f32x4 acc[4][4];
    #pragma unroll
    for (int m = 0; m < 4; ++m)
        #pragma unroll
        for (int n = 0; n < 4; ++n) acc[m][n] = (f32x4){0.f, 0.f, 0.f, 0.f};

#if !HAVE_GLL
    const int srow = t >> 1, sf0 = (t & 1) * 32;
#endif

    for (int fb = 0; fb < FF; fb += 64) {
        __syncthreads();
#if HAVE_GLL
        {
            const int gr = wave * 32 + (lane >> 3);
            const int gc = (lane & 7) * 8;
            #pragma unroll
            for (int i = 0; i < 4; ++i) {
                __builtin_amdgcn_global_load_lds(
                    (const unsigned int*)&X[(size_t)(rb + gr + 8 * i) * FF + fb + gc],
                    (unsigned int*)&As[(wave * 32 + 8 * i) * GSTR], 16, 0, 0);
                __builtin_amdgcn_global_load_lds(
                    (const unsigned int*)&Wt[(size_t)(cb + gr + 8 * i) * FF + fb + gc],
                    (unsigned int*)&Bs[(wave * 32 + 8 * i) * GSTR], 16, 0, 0);
            }
        }
#else
        #pragma unroll
        for (int s = 0; s < 4; ++s) {
            *(ushort8*)&As[srow * GSTR + sf0 + 8 * s] =
                *(const ushort8*)&X[(size_t)(rb + srow) * FF + fb + sf0 + 8 * s];
            *(ushort8*)&Bs[srow * GSTR + sf0 + 8 * s] =
                *(const ushort8*)&Wt[(size_t)(cb + srow) * FF + fb + sf0 + 8 * s];
        }
#endif
        __syncthreads();

        bf16x8 af[4][2], bf[4][2];
        #pragma unroll
        for (int m = 0; m < 4; ++m) {
            af[m][0] = *(const bf16x8*)&As[(wr * 64 + m * 16 + li) * GSTR + 8 * lg];
            af[m][1] = *(const bf16x8*)&As[(wr * 64 + m * 16 + li) * GSTR + 8 * lg + 32];
        }
        #pragma unroll
        for (int n = 0; n < 4; ++n) {
            bf[n][0] = *(const bf16x8*)&Bs[(wc * 64 + n * 16 + li) * GSTR + 8 * lg];
            bf[n][1] = *(const bf16x8*)&Bs[(wc * 64 + n * 16 + li) * GSTR + 8 * lg + 32];
        }
        #pragma unroll
        for (int m = 0; m < 4; ++m)
            #pragma unroll
            for (int n = 0; n < 4; ++n) {
                acc[m][n] = __builtin_amdgcn_mfma_f32_16x16x32_bf16(af[m][0], bf[n][0], acc[m][n], 0, 0, 0);
                acc[m][n] = __builtin_amdgcn_mfma_f32_16x16x32_bf16(af[m][1], bf[n][1], acc[m][n], 0, 0, 0);
            }
    }

    if (pj != 2) {
        #pragma unroll
        for (int m = 0; m < 4; ++m)
            #pragma unroll
            for (int n = 0; n < 4; ++n)
                #pragma unroll
                for (int r = 0; r < 4; ++r) {
                    int row = rb + wr * 64 + m * 16 + 4 * lg + r;
                    int col = cb + wc * 64 + n * 16 + li;
                    int b_ = row >> 10, n_ = row & 1023;
                    int h = col >> 6, k = col & 63;
                    P[((size_t)(b_ * HH + h) * NN + n_) * KK + k] = f2b(acc[m][n][r] + bias[col]);
                }
    } else {
        #pragma unroll
        for (int m = 0; m < 4; ++m)
            #pragma unroll
            for (int n = 0; n < 4; ++n) {
                int col = cb + wc * 64 + n * 16 + li;
                int h = col >> 6, k = col & 63;
                int row0 = rb + wr * 64 + m * 16 + 4 * lg;
                int b_ = row0 >> 10, n0 = row0 & 1023;
                float bsv = bias[col];
                ushort4v w;
                #pragma unroll
                for (int r = 0; r < 4; ++r) w[r] = f2b(acc[m][n][r] + bsv);
                *(ushort4v*)&P[((size_t)(b_ * HH + h) * KK + k) * NN + n0] = w;
            }
    }
}

// ---------------------------------------------------------------------------
// Kernel 2: MFMA flash attention — r5 body (T2-swizzled, known-good) with:
//  * adj via pre-permuted global stream: fragment loads = contiguous 512B/wave
//    b64 reads, no LDS, no barrier coupling (compiler pipelines them freely).
//  * K/V double-buffered in 32KB LDS, reg-staged; ONE barrier per iteration:
//    {issue loads mt+1 -> compute from buf[cur] -> write buf[cur^1] -> bar}.
//    Writes to cur^1 cannot race: no wave reads cur^1 between the enclosing
//    barriers. Staged loads get the whole compute phase to land.
//  Loop LDS traffic -29%, barriers 32->17, adj addressing = linear stream.
// ---------------------------------------------------------------------------
#define SWU(ROW, CU) (((ROW) << 6) + ((CU) ^ (((ROW) & 7) << 3)))

__global__ __launch_bounds__(256, 4) void attn_kernel(
    const u16* __restrict__ Pbase,
    const float* __restrict__ Wia, const float* __restrict__ Wib, const float* __restrict__ Win,
    const u16* __restrict__ AD, const u16* __restrict__ AinT,
    u16* __restrict__ msgs)
{
    // hw flat id -> logical (q, bh, agg); 1024 = 8 XCD chunks x 128
    const int flat = blockIdx.x;
    const int lf   = (flat & 7) * 128 + (flat >> 3);
    const int qblk = lf & 7;
    const int qb   = qblk * 128;
    const int bh   = (lf >> 3) & 31;
    const int agg  = lf >> 8;
    const int b = bh >> 3, h = bh & 7;
    const int t = threadIdx.x;
    const int lane = t & 63, wave = t >> 6;
    const int lg = lane >> 4, li = lane & 15;

    const u16 *Qp, *Kp, *Vp, *adjp; const float* ew;
    switch (agg) {
      case 0: Qp = Pbase;         ew = Wia; Kp = Pbase + 1*PSZ; Vp = Pbase + 2*PSZ; adjp = AD;          break;
      case 1: Qp = Pbase + 3*PSZ; ew = Wib; Kp = Pbase + 4*PSZ; Vp = Pbase + 5*PSZ; adjp = AD + 1*ADSZ; break;
      case 2: Qp = Pbase;         ew = Win; Kp = Pbase + 4*PSZ; Vp = Pbase + 2*PSZ; adjp = AD + 2*ADSZ; break;
      default:Qp = Pbase + 3*PSZ; ew = Win; Kp = Pbase + 1*PSZ; Vp = Pbase + 5*PSZ; adjp = AinT;        break;
    }
    const size_t bhoff = (size_t)(b * HH + h) * NN * KK;
    const u16* Qbh  = Qp + bhoff;       // [n][k] bf16
    const u16* Kbh  = Kp + bhoff;       // [n][k] bf16
    const u16* Vbh  = Vp + bhoff;       // [k][n] bf16 (pre-transposed)
    // permuted adj stream: [mt16][wave4][u2][t_4][lane64*4], per (agg,b,qblk)
    const u16* advs = adjp + ((size_t)b << 20) + (size_t)qblk * 131072u
                           + (unsigned)(wave * 2048 + lane * 4);

    __shared__ u16 SM[16384];           // 32 KB
    u16* preQ = SM;                     // 128x64 swz (preamble Q out)
    u16* preF = SM + 8192;              // 64x64 swz (preamble F1 staging)
    u16* preE = SM + 12288;             // 64x64 swz (preamble ewT)
    // loop: K buffers at SM+0 / SM+4096 ; V buffers at SM+8192 / SM+12288

    const int sr  = t >> 2;             // 0..63
    const int sc  = (t & 3) * 16;

    // ---------------- preamble: Q = F1 @ ew for 128 rows ----------------
    #pragma unroll
    for (int j = 0; j < 16; ++j)        // preE[l][k'] = ew[k'][l]
        preE[SWU(sc + j, sr)] = f2b(ew[sr * 64 + sc + j]);

    #pragma unroll
    for (int p = 0; p < 2; ++p) {
        __syncthreads();
        {
            const ushort8* src = (const ushort8*)&Qbh[(size_t)(qb + p * 64 + sr) * KK + sc];
            *(ushort8*)&preF[SWU(sr, sc)]     = src[0];
            *(ushort8*)&preF[SWU(sr, sc + 8)] = src[1];
        }
        __syncthreads();
        bf16x8 a0 = *(const bf16x8*)&preF[SWU(wave * 16 + li, 8 * lg)];
        bf16x8 a1 = *(const bf16x8*)&preF[SWU(wave * 16 + li, 8 * lg + 32)];
        #pragma unroll
        for (int t_ = 0; t_ < 4; ++t_) {
            bf16x8 b0 = *(const bf16x8*)&preE[SWU(li + 16 * t_, 8 * lg)];
            bf16x8 b1 = *(const bf16x8*)&preE[SWU(li + 16 * t_, 8 * lg + 32)];
            f32x4 q = {0.f, 0.f, 0.f, 0.f};
            q = __builtin_amdgcn_mfma_f32_16x16x32_bf16(a0, b0, q, 0, 0, 0);
            q = __builtin_amdgcn_mfma_f32_16x16x32_bf16(a1, b1, q, 0, 0, 0);
            #pragma unroll
            for (int r = 0; r < 4; ++r)
                preQ[SWU(p * 64 + wave * 16 + 4 * lg + r, li + 16 * t_)] = f2b(q[r]);
        }
    }
    __syncthreads();
    bf16x8 qB[2][2];
    #pragma unroll
    for (int u = 0; u < 2; ++u)
        #pragma unroll
        for (int c = 0; c < 2; ++c)
            qB[u][c] = *(const bf16x8*)&preQ[SWU(wave * 32 + u * 16 + li, 32 * c + 8 * lg)];
    __syncthreads();                    // preamble LDS dead; loop buffers free

    f32x4 oacc[2][4];
    #pragma unroll
    for (int u = 0; u < 2; ++u)
        #pragma unroll
        for (int f_ = 0; f_ < 4; ++f_) oacc[u][f_] = (f32x4){0.f, 0.f, 0.f, 0.f};
    float lsum[2] = {0.f, 0.f};

#if HAVE_MFMA16
    // ---- prologue: stage tile 0 into buffer 0 ----
    {
        const ushort8* ks = (const ushort8*)&Kbh[(size_t)sr * KK + sc];
        *(ushort8*)&SM[SWU(sr, sc)]            = ks[0];
        *(ushort8*)&SM[SWU(sr, sc + 8)]        = ks[1];
        const ushort8* vs = (const ushort8*)&Vbh[(size_t)sr * NN + sc];
        *(ushort8*)&SM[8192 + SWU(sr, sc)]     = vs[0];
        *(ushort8*)&SM[8192 + SWU(sr, sc + 8)] = vs[1];
    }
    __syncthreads();

    for (int mt = 0; mt < 16; ++mt) {
        const int cur = (mt & 1) * 4096;
        const u16* Kc = SM + cur;
        const u16* Vc = SM + 8192 + cur;

        // ---- issue next-tile K/V loads (consumed by ds_writes after compute) ----
        ushort8 kr0, kr1, vr0, vr1;
        if (mt < 15) {
            const int mb2 = (mt + 1) * 64;
            const ushort8* ks = (const ushort8*)&Kbh[(size_t)(mb2 + sr) * KK + sc];
            kr0 = ks[0]; kr1 = ks[1];
            const ushort8* vs = (const ushort8*)&Vbh[(size_t)sr * NN + mb2 + sc];
            vr0 = vs[0]; vr1 = vs[1];
        }

        // ---- adj fragments: contiguous b64 loads from the permuted stream ----
        ushort4v adv[2][4];
        {
            const u16* ap = advs + (size_t)mt * 8192;
            #pragma unroll
            for (int u = 0; u < 2; ++u)
                #pragma unroll
                for (int t_ = 0; t_ < 4; ++t_)
                    adv[u][t_] = *(const ushort4v*)&ap[(u * 4 + t_) * 256];
        }

        // ---- S^T + masked exp2 (fixed shift; exact) + cvt_pk pack ----
        bf16x4 pa[2][4];
        #pragma unroll
        for (int t_ = 0; t_ < 4; ++t_) {
            bf16x8 kb0 = *(const bf16x8*)&Kc[SWU(li + 16 * t_, 8 * lg)];
            bf16x8 kb1 = *(const bf16x8*)&Kc[SWU(li + 16 * t_, 8 * lg + 32)];
            #pragma unroll
            for (int u = 0; u < 2; ++u) {
                f32x4 s = {0.f, 0.f, 0.f, 0.f};
                __builtin_amdgcn_s_setprio(1);
                s = __builtin_amdgcn_mfma_f32_16x16x32_bf16(kb0, qB[u][0], s, 0, 0, 0);
                s = __builtin_amdgcn_mfma_f32_16x16x32_bf16(kb1, qB[u][1], s, 0, 0, 0);
                __builtin_amdgcn_s_setprio(0);
                float p0 = __builtin_amdgcn_exp2f(fmaf(s[0], b2f(adv[u][t_][0]), -SHIFT2));
                float p1 = __builtin_amdgcn_exp2f(fmaf(s[1], b2f(adv[u][t_][1]), -SHIFT2));
                float p2 = __builtin_amdgcn_exp2f(fmaf(s[2], b2f(adv[u][t_][2]), -SHIFT2));
                float p3 = __builtin_amdgcn_exp2f(fmaf(s[3], b2f(adv[u][t_][3]), -SHIFT2));
                lsum[u] += (p0 + p1) + (p2 + p3);
                unsigned w0, w1;
                asm("v_cvt_pk_bf16_f32 %0, %1, %2" : "=v"(w0) : "v"(p0), "v"(p1));
                asm("v_cvt_pk_bf16_f32 %0, %1, %2" : "=v"(w1) : "v"(p2), "v"(p3));
                union { uint2 u2; bf16x4 v; } pk;
                pk.u2.x = w0; pk.u2.y = w1;
                pa[u][t_] = pk.v;
            }
        }

        // ---- O += P @ V straight from registers (K=16 MFMA, b64 V-frags) ----
        __builtin_amdgcn_s_setprio(1);
        #pragma unroll
        for (int f_ = 0; f_ < 4; ++f_) {
            #pragma unroll
            for (int t_ = 0; t_ < 4; ++t_) {
                bf16x4 vb = *(const bf16x4*)&Vc[SWU(li + 16 * f_, 16 * t_ + 4 * lg)];
                oacc[0][f_] = __builtin_amdgcn_mfma_f32_16x16x16bf16_1k(pa[0][t_], vb, oacc[0][f_], 0, 0, 0);
                oacc[1][f_] = __builtin_amdgcn_mfma_f32_16x16x16bf16_1k(pa[1][t_], vb, oacc[1][f_], 0, 0, 0);
            }
        }
        __builtin_amdgcn_s_setprio(0);

        // ---- write staged regs into the other buffer; single barrier ----
        if (mt < 15) {
            const int nxt = ((mt & 1) ^ 1) * 4096;
            *(ushort8*)&SM[nxt + SWU(sr, sc)]            = kr0;
            *(ushort8*)&SM[nxt + SWU(sr, sc + 8)]        = kr1;
            *(ushort8*)&SM[8192 + nxt + SWU(sr, sc)]     = vr0;
            *(ushort8*)&SM[8192 + nxt + SWU(sr, sc + 8)] = vr1;
        }
        __syncthreads();
    }
#else
    // -------- fallback (non-gfx950): single-buffer, two barriers, LDS P ----
    u16* Kt = SM;                       // 64x64 swz
    u16* Vt = SM + 4096;                // 64x64 swz
    u16* Pq = SM + 8192;                // 128x64 swz (P staging)
    for (int mt = 0; mt < 16; ++mt) {
        const int mb = mt * 64;
        __syncthreads();
        {
            const ushort8* ks = (const ushort8*)&Kbh[(size_t)(mb + sr) * KK + sc];
            *(ushort8*)&Kt[SWU(sr, sc)]     = ks[0];
            *(ushort8*)&Kt[SWU(sr, sc + 8)] = ks[1];
            const ushort8* vs = (const ushort8*)&Vbh[(size_t)sr * NN + mb + sc];
            *(ushort8*)&Vt[SWU(sr, sc)]     = vs[0];
            *(ushort8*)&Vt[SWU(sr, sc + 8)] = vs[1];
        }
        __syncthreads();

        ushort4v adv[2][4];
        {
            const u16* ap = advs + (size_t)mt * 8192;
            #pragma unroll
            for (int u = 0; u < 2; ++u)
                #pragma unroll
                for (int t_ = 0; t_ < 4; ++t_)
                    adv[u][t_] = *(const ushort4v*)&ap[(u * 4 + t_) * 256];
        }

        #pragma unroll
        for (int t_ = 0; t_ < 4; ++t_) {
            bf16x8 kb0 = *(const bf16x8*)&Kt[SWU(li + 16 * t_, 8 * lg)];
            bf16x8 kb1 = *(const bf16x8*)&Kt[SWU(li + 16 * t_, 8 * lg + 32)];
            #pragma unroll
            for (int u = 0; u < 2; ++u) {
                f32x4 s = {0.f, 0.f, 0.f, 0.f};
                s = __builtin_amdgcn_mfma_f32_16x16x32_bf16(kb0, qB[u][0], s, 0, 0, 0);
                s = __builtin_amdgcn_mfma_f32_16x16x32_bf16(kb1, qB[u][1], s, 0, 0, 0);
                float p0 = __builtin_amdgcn_exp2f(fmaf(s[0], b2f(adv[u][t_][0]), -SHIFT2));
                float p1 = __builtin_amdgcn_exp2f(fmaf(s[1], b2f(adv[u][t_][1]), -SHIFT2));
                float p2 = __builtin_amdgcn_exp2f(fmaf(s[2], b2f(adv[u][t_][2]), -SHIFT2));
                float p3 = __builtin_amdgcn_exp2f(fmaf(s[3], b2f(adv[u][t_][3]), -SHIFT2));
                lsum[u] += (p0 + p1) + (p2 + p3);
                unsigned w0, w1;
                asm("v_cvt_pk_bf16_f32 %0, %1, %2" : "=v"(w0) : "v"(p0), "v"(p1));
                asm("v_cvt_pk_bf16_f32 %0, %1, %2" : "=v"(w1) : "v"(p2), "v"(p3));
                uint2 pd; pd.x = w0; pd.y = w1;
                *(uint2*)&Pq[SWU(wave * 32 + u * 16 + li, 16 * t_ + 4 * lg)] = pd;
            }
        }
        {
            bf16x8 pA[2][2];
            #pragma unroll
            for (int u = 0; u < 2; ++u) {
                pA[u][0] = *(const bf16x8*)&Pq[SWU(wave * 32 + u * 16 + li, 8 * lg)];
                pA[u][1] = *(const bf16x8*)&Pq[SWU(wave * 32 + u * 16 + li, 8 * lg + 32)];
            }
            #pragma unroll
            for (int f_ = 0; f_ < 4; ++f_) {
                bf16x8 vb0 = *(const bf16x8*)&Vt[SWU(li + 16 * f_, 8 * lg)];
                bf16x8 vb1 = *(const bf16x8*)&Vt[SWU(li + 16 * f_, 8 * lg + 32)];
                #pragma unroll
                for (int u = 0; u < 2; ++u) {
                    oacc[u][f_] = __builtin_amdgcn_mfma_f32_16x16x32_bf16(pA[u][0], vb0, oacc[u][f_], 0, 0, 0);
                    oacc[u][f_] = __builtin_amdgcn_mfma_f32_16x16x32_bf16(pA[u][1], vb1, oacc[u][f_], 0, 0, 0);
                }
            }
        }
    }
#endif

    // ---- epilogue: reduce l over 16-lane groups, normalize, write msgs ----
    #pragma unroll
    for (int u = 0; u < 2; ++u) {
        lsum[u] += __shfl_xor(lsum[u], 16);
        lsum[u] += __shfl_xor(lsum[u], 32);
    }
    #pragma unroll
    for (int u = 0; u < 2; ++u)
        #pragma unroll
        for (int r = 0; r < 4; ++r) {
            float inv = 1.f / __shfl(lsum[u], 4 * lg + r);
            int row = qb + wave * 32 + u * 16 + 4 * lg + r;
            u16* dst = msgs + (size_t)agg * PSZ + ((size_t)b * NN + row) * (HH * KK) + h * KK;
            #pragma unroll
            for (int f_ = 0; f_ < 4; ++f_)
                dst[li + 16 * f_] = f2b(oacc[u][f_][r] * inv);
        }
}

// ---------------------------------------------------------------------------
// Kernel 3: MFMA output projection, 64x128 tile (512 blocks = 2/CU).
// ---------------------------------------------------------------------------
__global__ __launch_bounds__(256) void out_kernel(
    const u16* __restrict__ ws,
    const float* __restrict__ bo, const float* __restrict__ bo2,
    float* __restrict__ out)
{
    const int z  = blockIdx.z;
    const u16* M1 = ws + MSOFF + (size_t)z * PSZ;
    const u16* M2 = ws + MSOFF + (size_t)(2 + z) * PSZ;
    const u16* Wb = ws + WOOFF;
    const int rb = blockIdx.y * 64;
    const int cb = blockIdx.x * 128;
    const int t  = threadIdx.x;
    const int lane = t & 63, wave = t >> 6;
    const int lg = lane >> 4, li = lane & 15;
    const int wr = wave >> 1, wc = wave & 1;

    __shared__ u16 A1s[64 * GSTR];
    __shared__ u16 A2s[64 * GSTR];
    __shared__ u16 Bs[128 * GSTR];

    f32x4 acc1[2][4], acc2[2][4];
    #pragma unroll
    for (int m = 0; m < 2; ++m)
        #pragma unroll
        for (int n = 0; n < 4; ++n) {
            acc1[m][n] = (f32x4){0.f, 0.f, 0.f, 0.f};
            acc2[m][n] = (f32x4){0.f, 0.f, 0.f, 0.f};
        }

    for (int fb = 0; fb < FF; fb += 64) {
        __syncthreads();
#if HAVE_GLL
        {
            const int lr = lane >> 3;
            const int gc = (lane & 7) * 8;
            #pragma unroll
            for (int i = 0; i < 2; ++i) {
                __builtin_amdgcn_global_load_lds(
                    (const unsigned int*)&M1[(size_t)(rb + wave * 16 + 8 * i + lr) * FF + fb + gc],
                    (unsigned int*)&A1s[(wave * 16 + 8 * i) * GSTR], 16, 0, 0);
                __builtin_amdgcn_global_load_lds(
                    (const unsigned int*)&M2[(size_t)(rb + wave * 16 + 8 * i + lr) * FF + fb + gc],
                    (unsigned int*)&A2s[(wave * 16 + 8 * i) * GSTR], 16, 0, 0);
            }
            #pragma unroll
            for (int i = 0; i < 4; ++i) {
                __builtin_amdgcn_global_load_lds(
                    (const unsigned int*)&Wb[(size_t)(cb + wave * 32 + 8 * i + lr) * FF + fb + gc],
                    (unsigned int*)&Bs[(wave * 32 + 8 * i) * GSTR], 16, 0, 0);
            }
        }
#else
        {
            int ar = t >> 2, ac = (t & 3) * 16;
            *(ushort8*)&A1s[ar * GSTR + ac]     = *(const ushort8*)&M1[(size_t)(rb + ar) * FF + fb + ac];
            *(ushort8*)&A1s[ar * GSTR + ac + 8] = *(const ushort8*)&M1[(size_t)(rb + ar) * FF + fb + ac + 8];
            *(ushort8*)&A2s[ar * GSTR + ac]     = *(const ushort8*)&M2[(size_t)(rb + ar) * FF + fb + ac];
            *(ushort8*)&A2s[ar * GSTR + ac + 8] = *(const ushort8*)&M2[(size_t)(rb + ar) * FF + fb + ac + 8];
            int br = t >> 1, bc = (t & 1) * 32;
            #pragma unroll
            for (int s = 0; s < 4; ++s)
                *(ushort8*)&Bs[br * GSTR + bc + 8 * s] =
                    *(const ushort8*)&Wb[(size_t)(cb + br) * FF + fb + bc + 8 * s];
        }
#endif
        __syncthreads();

        #pragma unroll
        for (int m = 0; m < 2; ++m) {
            bf16x8 a10 = *(const bf16x8*)&A1s[(wr * 32 + m * 16 + li) * GSTR + 8 * lg];
            bf16x8 a11 = *(const bf16x8*)&A1s[(wr * 32 + m * 16 + li) * GSTR + 8 * lg + 32];
            bf16x8 a20 = *(const bf16x8*)&A2s[(wr * 32 + m * 16 + li) * GSTR + 8 * lg];
            bf16x8 a21 = *(const bf16x8*)&A2s[(wr * 32 + m * 16 + li) * GSTR + 8 * lg + 32];
            #pragma unroll
            for (int n = 0; n < 4; ++n) {
                bf16x8 b0 = *(const bf16x8*)&Bs[(wc * 64 + n * 16 + li) * GSTR + 8 * lg];
                bf16x8 b1 = *(const bf16x8*)&Bs[(wc * 64 + n * 16 + li) * GSTR + 8 * lg + 32];
                acc1[m][n] = __builtin_amdgcn_mfma_f32_16x16x32_bf16(a10, b0, acc1[m][n], 0, 0, 0);
                acc1[m][n] = __builtin_amdgcn_mfma_f32_16x16x32_bf16(a11, b1, acc1[m][n], 0, 0, 0);
                acc2[m][n] = __builtin_amdgcn_mfma_f32_16x16x32_bf16(a20, b0, acc2[m][n], 0, 0, 0);
                acc2[m][n] = __builtin_amdgcn_mfma_f32_16x16x32_bf16(a21, b1, acc2[m][n], 0, 0, 0);
            }
        }
    }

    #pragma unroll
    for (int m = 0; m < 2; ++m)
        #pragma unroll
        for (int n = 0; n < 4; ++n)
            #pragma unroll
            for (int r = 0; r < 4; ++r) {
                int row = rb + wr * 32 + m * 16 + 4 * lg + r;
                int col = cb + wc * 64 + n * 16 + li;
                float v1 = fmaxf(acc1[m][n][r] + bo[col], 0.f);
                float v2 = fmaxf(acc2[m][n][r] + bo[col], 0.f);
                out[(size_t)z * (BB * NN * FF) + (size_t)row * FF + col] = v1 + v2 + 2.f * bo2[col];
            }
}

extern "C" void kernel_launch(void* const* d_in, const int* in_sizes, int n_in,
                              void* d_out, int out_size, void* d_ws, size_t ws_size,
                              hipStream_t stream) {
    const float* nfa  = (const float*)d_in[0];
    const float* nfb  = (const float*)d_in[1];
    const float* Aia  = (const float*)d_in[2];
    const float* Aib  = (const float*)d_in[3];
    const float* Ain  = (const float*)d_in[4];
    const float* W1   = (const float*)d_in[5];
    const float* b1   = (const float*)d_in[6];
    const float* W2   = (const float*)d_in[7];
    const float* b2   = (const float*)d_in[8];
    const float* W3   = (const float*)d_in[9];
    const float* b3   = (const float*)d_in[10];
    const float* Wia  = (const float*)d_in[11];
    const float* Wib  = (const float*)d_in[12];
    const float* Win  = (const float*)d_in[13];
    const float* Wout = (const float*)d_in[14];
    const float* bo   = (const float*)d_in[15];
    const float* bo2  = (const float*)d_in[16];

    u16* ws = (u16*)d_ws;
    float* out = (float*)d_out;

    prep_kernel<<<1536, 256, 0, stream>>>(nfa, nfb, Wout, W1, W2, W3, ws);
    perm_kernel<<<dim3(128, 4, 3), 256, 0, stream>>>(Aia, Aib, Ain, ws);
    proj_kernel<<<dim3(4, 32, 6), 256, 0, stream>>>(b1, b2, b3, ws);
    // permuted AinT overwrites the (now dead) Xa/Xb region
    permt_kernel<<<dim3(128, 4), 256, 0, stream>>>(Ain, ws + XAOFF);
    attn_kernel<<<1024, 256, 0, stream>>>(ws + PBOFF, Wia, Wib, Win, ws + ADOFF, ws + XAOFF, ws + MSOFF);
    out_kernel<<<dim3(4, 64, 2), 256, 0, stream>>>(ws, bo, bo2, out);
}